// Round 8
// baseline (1226.029 us; speedup 1.0000x reference)
//
#include <hip/hip_runtime.h>

typedef short v8s __attribute__((ext_vector_type(8)));
typedef float v4f __attribute__((ext_vector_type(4)));

__device__ __forceinline__ unsigned short f2bf(float x) {
  unsigned u = __float_as_uint(x);
  u = u + 0x7FFFu + ((u >> 16) & 1u);
  return (unsigned short)(u >> 16);
}
__device__ __forceinline__ float bf2f(unsigned short b) {
  return __uint_as_float(((unsigned)b) << 16);
}
__device__ __forceinline__ float sigmoidf_(float x) {
  return 1.f / (1.f + __expf(-x));
}
__device__ __forceinline__ float tanhf_(float x) {
  x = fminf(fmaxf(x, -20.f), 20.f);
  float e2 = __expf(2.f * x);
  return (e2 - 1.f) / (e2 + 1.f);
}
// LDS swizzle: XOR byte-bits 4-6 with row&7 (rows are 128 B) -> 2-way max.
__device__ __forceinline__ int swz(int row, int byteInRow) {
  return row * 128 + (byteInRow ^ ((row & 7) << 4));
}

// ---------- merged weight prep ----------
// frag layout per weight: idx = ((p*nkc + kc)*nct + ct)*512 + lane*8 + j
// value: W[t][kc*32+(lane>>4)*8+j][ct*16+(lane&15)], p=0 hi, p=1 lo.
__device__ __forceinline__ void wprep_one(const float* W, unsigned short* O,
                                          int K, int J, int idx) {
  int nkc = K >> 5, nct = J >> 4;
  int j = idx & 7, lane = (idx >> 3) & 63;
  int rest = idx >> 9;
  int ct = rest % nct; rest /= nct;
  int kc = rest % nkc; rest /= nkc;
  int p = rest & 1, t = rest >> 1;
  int row = kc * 32 + (lane >> 4) * 8 + j;
  int col = ct * 16 + (lane & 15);
  float v = W[(size_t)t * K * J + (size_t)row * J + col];
  unsigned short hi = f2bf(v);
  O[idx] = p ? f2bf(v - bf2f(hi)) : hi;
}

__global__ void k_wprep_all(
    const float* eW0, const float* eW1, const float* projW,
    const float* g0Wx, const float* g0Wh, const float* g1Wx, const float* g1Wh,
    unsigned short* eW0f, unsigned short* eW1f, unsigned short* projf,
    unsigned short* g0xf, unsigned short* g0hf,
    unsigned short* g1xf, unsigned short* g1hf) {
  int rel = blockIdx.x * 256 + threadIdx.x;
  if (rel < 65536) { wprep_one(eW0, eW0f, 64, 64, rel); return; }
  rel -= 65536;
  if (rel < 65536) { wprep_one(eW1, eW1f, 64, 64, rel); return; }
  rel -= 65536;
  if (rel < 8192)  { wprep_one(projW, projf, 64, 64, rel); return; }
  rel -= 8192;
  if (rel < 24576) { wprep_one(g0Wx, g0xf, 64, 192, rel); return; }
  rel -= 24576;
  if (rel < 24576) { wprep_one(g0Wh, g0hf, 64, 192, rel); return; }
  rel -= 24576;
  if (rel < 49152) { wprep_one(g1Wx, g1xf, 128, 192, rel); return; }
  rel -= 49152;
  if (rel < 24576) { wprep_one(g1Wh, g1hf, 64, 192, rel); return; }
}

// ---------- embedding gather (coalesced: 64 lanes = 64 features) ----------
__global__ __launch_bounds__(256) void k_embed(
    const int* __restrict__ toks, const float* __restrict__ embed,
    unsigned short* __restrict__ eh, unsigned short* __restrict__ el, int N) {
  int w = threadIdx.x >> 6, lane = threadIdx.x & 63;
  int n = blockIdx.x * 4 + w;
  if (n >= N) return;
  float acc = 0.f;
#pragma unroll
  for (int s = 0; s < 5; ++s)
    acc += embed[(size_t)toks[n * 5 + s] * 64 + lane];
  float v = acc * 0.2f;
  unsigned short h = f2bf(v);
  eh[(size_t)n * 64 + lane] = h;
  el[(size_t)n * 64 + lane] = f2bf(v - bf2f(h));
}

// ---------- CSR build: each thread handles fwd+bwd of one edge ----------
__global__ void k_counts(const int* __restrict__ adj, int* __restrict__ counts, int E) {
  int e = blockIdx.x * 256 + threadIdx.x;
  if (e >= E) return;
  int t4 = blockIdx.y;
  int2 ab = *(const int2*)&adj[(size_t)(t4 * E + e) * 2];
  atomicAdd(&counts[ab.y], 1);
  atomicAdd(&counts[ab.x], 1);
}

__global__ __launch_bounds__(1024) void k_scan(const int* __restrict__ counts,
                                               int* __restrict__ offsets,
                                               int* __restrict__ cursor, int n) {
  __shared__ int part[1024];
  int tid = threadIdx.x;
  int chunk = (((n + 1023) >> 10) + 3) & ~3;
  int begin = tid * chunk;
  int end = min(begin + chunk, n);
  int s = 0;
  int i = begin;
  for (; i + 4 <= end; i += 4) {
    int4 v = *(const int4*)&counts[i];
    s += v.x + v.y + v.z + v.w;
  }
  for (; i < end; ++i) s += counts[i];
  part[tid] = s;
  __syncthreads();
  for (int off = 1; off < 1024; off <<= 1) {
    int v = (tid >= off) ? part[tid - off] : 0;
    __syncthreads();
    part[tid] += v;
    __syncthreads();
  }
  int run = part[tid] - s;
  i = begin;
  for (; i + 4 <= end; i += 4) {
    int4 c = *(const int4*)&counts[i];
    int4 o;
    o.x = run; o.y = run + c.x; o.z = o.y + c.y; o.w = o.z + c.z;
    *(int4*)&offsets[i] = o;
    *(int4*)&cursor[i] = o;
    run = o.w + c.w;
  }
  for (; i < end; ++i) {
    offsets[i] = run; cursor[i] = run; run += counts[i];
  }
  if (tid == 1023) offsets[n] = part[1023];
}

__global__ void k_fill(const int* __restrict__ adj, int* __restrict__ cursor,
                       int* __restrict__ entries, int E, int N) {
  int e = blockIdx.x * 256 + threadIdx.x;
  if (e >= E) return;
  int t4 = blockIdx.y;
  int2 ab = *(const int2*)&adj[(size_t)(t4 * E + e) * 2];
  int p1 = atomicAdd(&cursor[ab.y], 1);
  entries[p1] = t4 * N + ab.x;
  int p2 = atomicAdd(&cursor[ab.x], 1);
  entries[p2] = (t4 + 4) * N + ab.y;
}

// ---------- proj GEMM: h_init = emb @ projW ----------
__global__ __launch_bounds__(256) void k_proj(
    const unsigned short* __restrict__ A0h, const unsigned short* __restrict__ A0l,
    const unsigned short* __restrict__ Wf,
    unsigned short* __restrict__ h_hi, unsigned short* __restrict__ h_lo,
    unsigned short* __restrict__ hinit_b, int N) {
  int tid = threadIdx.x;
  int wv = tid >> 6, lane = tid & 63;
  int lr = lane & 15, lg = lane >> 4;
  int m0 = blockIdx.x * 128 + wv * 32;
  v4f acc[2][4] = {};
#pragma unroll
  for (int kc = 0; kc < 2; ++kc) {
    v8s ah[2], al[2];
#pragma unroll
    for (int mt = 0; mt < 2; ++mt) {
      int row = min(m0 + mt * 16 + lr, N - 1);
      size_t off = (size_t)row * 64 + kc * 32 + lg * 8;
      ah[mt] = *(const v8s*)&A0h[off];
      al[mt] = *(const v8s*)&A0l[off];
    }
#pragma unroll
    for (int ct = 0; ct < 4; ++ct) {
      v8s bh = *(const v8s*)&Wf[((size_t)(kc * 4 + ct)) * 512 + lane * 8];
      v8s bl = *(const v8s*)&Wf[((size_t)((2 + kc) * 4 + ct)) * 512 + lane * 8];
#pragma unroll
      for (int mt = 0; mt < 2; ++mt) {
        acc[mt][ct] = __builtin_amdgcn_mfma_f32_16x16x32_bf16(ah[mt], bh, acc[mt][ct], 0, 0, 0);
        acc[mt][ct] = __builtin_amdgcn_mfma_f32_16x16x32_bf16(al[mt], bh, acc[mt][ct], 0, 0, 0);
        acc[mt][ct] = __builtin_amdgcn_mfma_f32_16x16x32_bf16(ah[mt], bl, acc[mt][ct], 0, 0, 0);
      }
    }
  }
#pragma unroll
  for (int ct = 0; ct < 4; ++ct)
#pragma unroll
    for (int mt = 0; mt < 2; ++mt)
#pragma unroll
      for (int r = 0; r < 4; ++r) {
        int m = m0 + mt * 16 + lg * 4 + r;
        if (m >= N) continue;
        int col = ct * 16 + lr;
        float v = acc[mt][ct][r];
        unsigned short hb = f2bf(v);
        h_hi[(size_t)m * 64 + col] = hb;
        h_lo[(size_t)m * 64 + col] = f2bf(v - bf2f(hb));
        hinit_b[(size_t)m * 64 + col] = hb;
      }
}

// ---------- initial transform: Ht[t][n] = h[n] @ W[t], 2 types per block ----------
__global__ __launch_bounds__(256) void k_mm_t(
    const unsigned short* __restrict__ A0h, const unsigned short* __restrict__ A0l,
    const unsigned short* __restrict__ Wf, unsigned short* __restrict__ C16,
    int N) {
  int tid = threadIdx.x;
  int wv = tid >> 6, lane = tid & 63;
  int lr = lane & 15, lg = lane >> 4;
  int y = blockIdx.y;
  const unsigned short* W0 = Wf + (size_t)y * 8192;
  const unsigned short* W1 = Wf + (size_t)(y + 4) * 8192;
  unsigned short* C0 = C16 + (size_t)y * N * 64;
  unsigned short* C1 = C16 + (size_t)(y + 4) * N * 64;
  int m0 = blockIdx.x * 128 + wv * 32;
  v4f acc0[2][4] = {}, acc1[2][4] = {};
#pragma unroll
  for (int kc = 0; kc < 2; ++kc) {
    v8s ah[2], al[2];
#pragma unroll
    for (int mt = 0; mt < 2; ++mt) {
      int row = min(m0 + mt * 16 + lr, N - 1);
      size_t off = (size_t)row * 64 + kc * 32 + lg * 8;
      ah[mt] = *(const v8s*)&A0h[off];
      al[mt] = *(const v8s*)&A0l[off];
    }
#pragma unroll
    for (int ct = 0; ct < 4; ++ct) {
      v8s bh0 = *(const v8s*)&W0[((size_t)(kc * 4 + ct)) * 512 + lane * 8];
      v8s bl0 = *(const v8s*)&W0[((size_t)((2 + kc) * 4 + ct)) * 512 + lane * 8];
      v8s bh1 = *(const v8s*)&W1[((size_t)(kc * 4 + ct)) * 512 + lane * 8];
      v8s bl1 = *(const v8s*)&W1[((size_t)((2 + kc) * 4 + ct)) * 512 + lane * 8];
#pragma unroll
      for (int mt = 0; mt < 2; ++mt) {
        acc0[mt][ct] = __builtin_amdgcn_mfma_f32_16x16x32_bf16(ah[mt], bh0, acc0[mt][ct], 0, 0, 0);
        acc0[mt][ct] = __builtin_amdgcn_mfma_f32_16x16x32_bf16(al[mt], bh0, acc0[mt][ct], 0, 0, 0);
        acc0[mt][ct] = __builtin_amdgcn_mfma_f32_16x16x32_bf16(ah[mt], bl0, acc0[mt][ct], 0, 0, 0);
        acc1[mt][ct] = __builtin_amdgcn_mfma_f32_16x16x32_bf16(ah[mt], bh1, acc1[mt][ct], 0, 0, 0);
        acc1[mt][ct] = __builtin_amdgcn_mfma_f32_16x16x32_bf16(al[mt], bh1, acc1[mt][ct], 0, 0, 0);
        acc1[mt][ct] = __builtin_amdgcn_mfma_f32_16x16x32_bf16(ah[mt], bl1, acc1[mt][ct], 0, 0, 0);
      }
    }
  }
#pragma unroll
  for (int ct = 0; ct < 4; ++ct)
#pragma unroll
    for (int mt = 0; mt < 2; ++mt)
#pragma unroll
      for (int r = 0; r < 4; ++r) {
        int m = m0 + mt * 16 + lg * 4 + r;
        if (m < N) {
          C0[(size_t)m * 64 + ct * 16 + lr] = f2bf(acc0[mt][ct][r]);
          C1[(size_t)m * 64 + ct * 16 + lr] = f2bf(acc1[mt][ct][r]);
        }
      }
}

// ---------- fused iteration: aggmax -> GRU -> (transform) ----------
// One block = 128 nodes. All LDS traffic is wave-local (each wave owns its 32
// rows through every phase) so NO __syncthreads is needed.
// FINAL=0: gru0 (x=msg from LDS), then transform new h -> HtW (8 types).
// FINAL=1: gru1 (x=concat(hinit global, msg LDS)), writes f32 out; no transform.
template <int FINAL>
__global__ __launch_bounds__(256) void k_iter(
    const unsigned short* __restrict__ HtR, const int* __restrict__ offsets,
    const int* __restrict__ entries,
    unsigned short* __restrict__ hh, unsigned short* __restrict__ hl,
    const unsigned short* __restrict__ hinit_b,
    const unsigned short* __restrict__ Wxf, const unsigned short* __restrict__ Whf,
    const float* __restrict__ bias, const unsigned short* __restrict__ eWf,
    unsigned short* __restrict__ HtW, float* __restrict__ outF, int N) {
  __shared__ __align__(16) char lds_msg[128 * 128];                 // 16 KB
  __shared__ __align__(16) char lds_hs[FINAL ? 16 : 2 * 128 * 128]; // 32 KB
  int tid = threadIdx.x;
  int wv = tid >> 6, lane = tid & 63;
  int lr = lane & 15, lg = lane >> 4;
  int lbase = wv * 32;                 // this wave's local row base
  int m0 = blockIdx.x * 128 + lbase;   // global row base

  // ---- phase 1: segment-max for this wave's 32 nodes -> lds_msg ----
  int g = lane >> 4, q = lane & 15;
  for (int i32 = 0; i32 < 32; ++i32) {
    int n = min(m0 + i32, N - 1);
    int beg = offsets[n], end = offsets[n + 1];
    float a0 = -3.4e38f, a1 = a0, a2 = a0, a3 = a0;
    float b0 = a0, b1 = a0, b2 = a0, b3 = a0;
    int i = beg;
    for (; i + 8 <= end; i += 8) {
      int eA = entries[i + g];
      int eB = entries[i + 4 + g];
      ushort4 va = *(const ushort4*)&HtR[(size_t)eA * 64 + q * 4];
      ushort4 vb = *(const ushort4*)&HtR[(size_t)eB * 64 + q * 4];
      a0 = fmaxf(a0, bf2f(va.x)); a1 = fmaxf(a1, bf2f(va.y));
      a2 = fmaxf(a2, bf2f(va.z)); a3 = fmaxf(a3, bf2f(va.w));
      b0 = fmaxf(b0, bf2f(vb.x)); b1 = fmaxf(b1, bf2f(vb.y));
      b2 = fmaxf(b2, bf2f(vb.z)); b3 = fmaxf(b3, bf2f(vb.w));
    }
    for (; i < end; i += 4) {
      int idx = min(i + g, end - 1);
      int e = entries[idx];
      ushort4 va = *(const ushort4*)&HtR[(size_t)e * 64 + q * 4];
      a0 = fmaxf(a0, bf2f(va.x)); a1 = fmaxf(a1, bf2f(va.y));
      a2 = fmaxf(a2, bf2f(va.z)); a3 = fmaxf(a3, bf2f(va.w));
    }
    a0 = fmaxf(a0, b0); a1 = fmaxf(a1, b1); a2 = fmaxf(a2, b2); a3 = fmaxf(a3, b3);
    a0 = fmaxf(a0, __shfl_xor(a0, 16)); a1 = fmaxf(a1, __shfl_xor(a1, 16));
    a2 = fmaxf(a2, __shfl_xor(a2, 16)); a3 = fmaxf(a3, __shfl_xor(a3, 16));
    a0 = fmaxf(a0, __shfl_xor(a0, 32)); a1 = fmaxf(a1, __shfl_xor(a1, 32));
    a2 = fmaxf(a2, __shfl_xor(a2, 32)); a3 = fmaxf(a3, __shfl_xor(a3, 32));
    if (g == 0) {
      ushort4 o;
      if (end > beg) {
        o.x = f2bf(a0); o.y = f2bf(a1); o.z = f2bf(a2); o.w = f2bf(a3);
      } else {
        o.x = 0; o.y = 0; o.z = 0; o.w = 0;
      }
      int row = lbase + i32;
      *(ushort4*)(lds_msg + swz(row, q * 8)) = o;
    }
  }

  // ---- phase 2: fused GRU ----
  const int NKCX = FINAL ? 4 : 2;
  v4f acc[2][12] = {};   // xr,xu,xc (+hr,hu merged)
  v4f acch[2][4] = {};   // hc separate
#pragma unroll
  for (int kc = 0; kc < NKCX; ++kc) {
    int kcl = kc & 1;
    v8s ax[2];
#pragma unroll
    for (int mt = 0; mt < 2; ++mt) {
      if (FINAL && kc < 2) {
        int row = min(m0 + mt * 16 + lr, N - 1);
        ax[mt] = *(const v8s*)&hinit_b[(size_t)row * 64 + kcl * 32 + lg * 8];
      } else {
        int row = lbase + mt * 16 + lr;
        ax[mt] = *(const v8s*)(lds_msg + swz(row, kcl * 64 + lg * 16));
      }
    }
#pragma unroll
    for (int ct = 0; ct < 12; ++ct) {
      v8s bh = *(const v8s*)&Wxf[((size_t)(kc * 12 + ct)) * 512 + lane * 8];
      v8s bl = *(const v8s*)&Wxf[((size_t)((NKCX + kc) * 12 + ct)) * 512 + lane * 8];
#pragma unroll
      for (int mt = 0; mt < 2; ++mt) {
        acc[mt][ct] = __builtin_amdgcn_mfma_f32_16x16x32_bf16(ax[mt], bh, acc[mt][ct], 0, 0, 0);
        acc[mt][ct] = __builtin_amdgcn_mfma_f32_16x16x32_bf16(ax[mt], bl, acc[mt][ct], 0, 0, 0);
      }
    }
  }
#pragma unroll
  for (int kc = 0; kc < 2; ++kc) {
    v8s ah[2], al[2];
#pragma unroll
    for (int mt = 0; mt < 2; ++mt) {
      int row = min(m0 + mt * 16 + lr, N - 1);
      size_t off = (size_t)row * 64 + kc * 32 + lg * 8;
      ah[mt] = *(const v8s*)&hh[off];
      al[mt] = *(const v8s*)&hl[off];
    }
#pragma unroll
    for (int ct = 0; ct < 12; ++ct) {
      v8s bh = *(const v8s*)&Whf[((size_t)(kc * 12 + ct)) * 512 + lane * 8];
      v8s bl = *(const v8s*)&Whf[((size_t)((2 + kc) * 12 + ct)) * 512 + lane * 8];
#pragma unroll
      for (int mt = 0; mt < 2; ++mt) {
        v4f* d = (ct < 8) ? &acc[mt][ct] : &acch[mt][ct - 8];
        *d = __builtin_amdgcn_mfma_f32_16x16x32_bf16(ah[mt], bh, *d, 0, 0, 0);
        *d = __builtin_amdgcn_mfma_f32_16x16x32_bf16(al[mt], bh, *d, 0, 0, 0);
        *d = __builtin_amdgcn_mfma_f32_16x16x32_bf16(ah[mt], bl, *d, 0, 0, 0);
      }
    }
  }
  // gate epilogue: write global h (non-final) or out (final); stage h in LDS.
#pragma unroll
  for (int mt = 0; mt < 2; ++mt)
#pragma unroll
    for (int ctg = 0; ctg < 4; ++ctg)
#pragma unroll
      for (int r = 0; r < 4; ++r) {
        int m = m0 + mt * 16 + lg * 4 + r;
        int col = ctg * 16 + lr;
        unsigned short hbv = hh[(size_t)min(m, N - 1) * 64 + col];
        unsigned short hlv = hl[(size_t)min(m, N - 1) * 64 + col];
        float hv = bf2f(hbv) + bf2f(hlv);
        float rr = sigmoidf_(acc[mt][ctg][r] + bias[col]);
        float uu = sigmoidf_(acc[mt][ctg + 4][r] + bias[64 + col]);
        float cc = tanhf_(acc[mt][ctg + 8][r] + bias[128 + col] + rr * acch[mt][ctg][r]);
        float ho = uu * hv + (1.f - uu) * cc;
        if (FINAL) {
          if (m < N) outF[(size_t)m * 64 + col] = ho;
        } else {
          unsigned short ohi = f2bf(ho);
          unsigned short olo = f2bf(ho - bf2f(ohi));
          if (m < N) {
            hh[(size_t)m * 64 + col] = ohi;
            hl[(size_t)m * 64 + col] = olo;
          }
          int row = lbase + mt * 16 + lg * 4 + r;
          *(unsigned short*)(lds_hs + swz(row, col * 2)) = ohi;
          *(unsigned short*)(lds_hs + 128 * 128 + swz(row, col * 2)) = olo;
        }
      }

  if (FINAL) return;

  // ---- phase 3: transform new h -> HtW for all 8 types (2 per pass) ----
  v8s tah[2][2], tal[2][2];  // [kc][mt]
#pragma unroll
  for (int kc = 0; kc < 2; ++kc)
#pragma unroll
    for (int mt = 0; mt < 2; ++mt) {
      int row = lbase + mt * 16 + lr;
      tah[kc][mt] = *(const v8s*)(lds_hs + swz(row, kc * 64 + lg * 16));
      tal[kc][mt] = *(const v8s*)(lds_hs + 128 * 128 + swz(row, kc * 64 + lg * 16));
    }
#pragma unroll
  for (int y = 0; y < 4; ++y) {
    const unsigned short* W0 = eWf + (size_t)y * 8192;
    const unsigned short* W1 = eWf + (size_t)(y + 4) * 8192;
    unsigned short* C0 = HtW + (size_t)y * N * 64;
    unsigned short* C1 = HtW + (size_t)(y + 4) * N * 64;
    v4f acc0[2][4] = {}, acc1[2][4] = {};
#pragma unroll
    for (int kc = 0; kc < 2; ++kc)
#pragma unroll
      for (int ct = 0; ct < 4; ++ct) {
        v8s bh0 = *(const v8s*)&W0[((size_t)(kc * 4 + ct)) * 512 + lane * 8];
        v8s bl0 = *(const v8s*)&W0[((size_t)((2 + kc) * 4 + ct)) * 512 + lane * 8];
        v8s bh1 = *(const v8s*)&W1[((size_t)(kc * 4 + ct)) * 512 + lane * 8];
        v8s bl1 = *(const v8s*)&W1[((size_t)((2 + kc) * 4 + ct)) * 512 + lane * 8];
#pragma unroll
        for (int mt = 0; mt < 2; ++mt) {
          acc0[mt][ct] = __builtin_amdgcn_mfma_f32_16x16x32_bf16(tah[kc][mt], bh0, acc0[mt][ct], 0, 0, 0);
          acc0[mt][ct] = __builtin_amdgcn_mfma_f32_16x16x32_bf16(tal[kc][mt], bh0, acc0[mt][ct], 0, 0, 0);
          acc0[mt][ct] = __builtin_amdgcn_mfma_f32_16x16x32_bf16(tah[kc][mt], bl0, acc0[mt][ct], 0, 0, 0);
          acc1[mt][ct] = __builtin_amdgcn_mfma_f32_16x16x32_bf16(tah[kc][mt], bh1, acc1[mt][ct], 0, 0, 0);
          acc1[mt][ct] = __builtin_amdgcn_mfma_f32_16x16x32_bf16(tal[kc][mt], bh1, acc1[mt][ct], 0, 0, 0);
          acc1[mt][ct] = __builtin_amdgcn_mfma_f32_16x16x32_bf16(tah[kc][mt], bl1, acc1[mt][ct], 0, 0, 0);
        }
      }
#pragma unroll
    for (int ct = 0; ct < 4; ++ct)
#pragma unroll
      for (int mt = 0; mt < 2; ++mt)
#pragma unroll
        for (int r = 0; r < 4; ++r) {
          int m = m0 + mt * 16 + lg * 4 + r;
          if (m < N) {
            C0[(size_t)m * 64 + ct * 16 + lr] = f2bf(acc0[mt][ct][r]);
            C1[(size_t)m * 64 + ct * 16 + lr] = f2bf(acc1[mt][ct][r]);
          }
        }
  }
}

extern "C" void kernel_launch(void* const* d_in, const int* in_sizes, int n_in,
                              void* d_out, int out_size, void* d_ws, size_t ws_size,
                              hipStream_t stream) {
  const int*   toks  = (const int*)d_in[0];
  const int*   adj   = (const int*)d_in[1];
  const float* embed = (const float*)d_in[2];
  const float* projW = (const float*)d_in[3];
  const float* eW0   = (const float*)d_in[4];
  const float* eW1   = (const float*)d_in[5];
  const float* g0Wx  = (const float*)d_in[6];
  const float* g0Wh  = (const float*)d_in[7];
  const float* g0b   = (const float*)d_in[8];
  const float* g1Wx  = (const float*)d_in[9];
  const float* g1Wh  = (const float*)d_in[10];
  const float* g1b   = (const float*)d_in[11];
  float* out = (float*)d_out;

  int N = in_sizes[0] / 5;
  int E = in_sizes[1] / 8;
  size_t ND = (size_t)N * 64;

  char* p = (char*)d_ws;
  unsigned short* Ht0     = (unsigned short*)p; p += 8 * ND * 2;   // 61.4 MB
  unsigned short* Ht1     = (unsigned short*)p; p += 8 * ND * 2;   // 61.4 MB
  unsigned short* h_hi    = (unsigned short*)p; p += ND * 2;
  unsigned short* h_lo    = (unsigned short*)p; p += ND * 2;
  unsigned short* hinit_b = (unsigned short*)p; p += ND * 2;
  int* offsets = (int*)p; p += (size_t)(N + 64) * sizeof(int);
  int* cnt_cur = (int*)p; p += (size_t)(N + 64) * sizeof(int);
  int* entries = (int*)p; p += (size_t)8 * E * sizeof(int);
  unsigned short* eW0f  = (unsigned short*)p; p += 65536 * 2;
  unsigned short* eW1f  = (unsigned short*)p; p += 65536 * 2;
  unsigned short* projf = (unsigned short*)p; p += 8192 * 2;
  unsigned short* g0xf  = (unsigned short*)p; p += 24576 * 2;
  unsigned short* g0hf  = (unsigned short*)p; p += 24576 * 2;
  unsigned short* g1xf  = (unsigned short*)p; p += 49152 * 2;
  unsigned short* g1hf  = (unsigned short*)p; p += 24576 * 2;
  if ((size_t)(p - (char*)d_ws) > ws_size) return;

  // init-phase aliases inside Ht0 (consumed by k_proj before k_mm_t writes Ht0)
  unsigned short* emb_h = Ht0;
  unsigned short* emb_l = Ht0 + ND;

  int g128 = (N + 127) / 128;
  int g4 = (N + 3) / 4;

  k_wprep_all<<<1024, 256, 0, stream>>>(eW0, eW1, projW, g0Wx, g0Wh, g1Wx, g1Wh,
                                        eW0f, eW1f, projf, g0xf, g0hf, g1xf, g1hf);
  hipMemsetAsync(cnt_cur, 0, (size_t)N * sizeof(int), stream);
  dim3 egrid((E + 255) / 256, 4);
  k_counts<<<egrid, 256, 0, stream>>>(adj, cnt_cur, E);
  k_embed<<<g4, 256, 0, stream>>>(toks, embed, emb_h, emb_l, N);
  k_proj<<<g128, 256, 0, stream>>>(emb_h, emb_l, projf, h_hi, h_lo, hinit_b, N);
  k_scan<<<1, 1024, 0, stream>>>(cnt_cur, offsets, cnt_cur, N);
  k_fill<<<egrid, 256, 0, stream>>>(adj, cnt_cur, entries, E, N);
  // initial transform: h_init -> Ht0
  k_mm_t<<<dim3(g128, 4), 256, 0, stream>>>(h_hi, h_lo, eW0f, Ht0, N);

  unsigned short* bufs[2] = {Ht0, Ht1};
  for (int it = 0; it < 7; ++it) {
    unsigned short* HtR = bufs[it & 1];
    unsigned short* HtW = bufs[(it + 1) & 1];
    // last gru0 iteration (it==6) must transform with eW1 for the final layer
    const unsigned short* ef = (it < 6) ? eW0f : eW1f;
    k_iter<0><<<g128, 256, 0, stream>>>(HtR, offsets, entries, h_hi, h_lo,
                                        hinit_b, g0xf, g0hf, g0b, ef,
                                        HtW, nullptr, N);
  }
  k_iter<1><<<g128, 256, 0, stream>>>(bufs[1], offsets, entries, h_hi, h_lo,
                                      hinit_b, g1xf, g1hf, g1b, nullptr,
                                      nullptr, out, N);
}

// Round 9
// 1113.386 us; speedup vs baseline: 1.1012x; 1.1012x over previous
//
#include <hip/hip_runtime.h>

typedef short v8s __attribute__((ext_vector_type(8)));
typedef float v4f __attribute__((ext_vector_type(4)));

__device__ __forceinline__ unsigned short f2bf(float x) {
  unsigned u = __float_as_uint(x);
  u = u + 0x7FFFu + ((u >> 16) & 1u);
  return (unsigned short)(u >> 16);
}
__device__ __forceinline__ float bf2f(unsigned short b) {
  return __uint_as_float(((unsigned)b) << 16);
}
__device__ __forceinline__ float sigmoidf_(float x) {
  return 1.f / (1.f + __expf(-x));
}
__device__ __forceinline__ float tanhf_(float x) {
  x = fminf(fmaxf(x, -20.f), 20.f);
  float e2 = __expf(2.f * x);
  return (e2 - 1.f) / (e2 + 1.f);
}
// LDS swizzle: XOR byte-bits 4-6 with row&7 (rows are 128 B) -> 2-way max.
__device__ __forceinline__ int swz(int row, int byteInRow) {
  return row * 128 + (byteInRow ^ ((row & 7) << 4));
}

// ---------- merged weight prep ----------
// frag layout per weight: idx = ((p*nkc + kc)*nct + ct)*512 + lane*8 + j
// value: W[t][kc*32+(lane>>4)*8+j][ct*16+(lane&15)], p=0 hi, p=1 lo.
__device__ __forceinline__ void wprep_one(const float* W, unsigned short* O,
                                          int K, int J, int idx) {
  int nkc = K >> 5, nct = J >> 4;
  int j = idx & 7, lane = (idx >> 3) & 63;
  int rest = idx >> 9;
  int ct = rest % nct; rest /= nct;
  int kc = rest % nkc; rest /= nkc;
  int p = rest & 1, t = rest >> 1;
  int row = kc * 32 + (lane >> 4) * 8 + j;
  int col = ct * 16 + (lane & 15);
  float v = W[(size_t)t * K * J + (size_t)row * J + col];
  unsigned short hi = f2bf(v);
  O[idx] = p ? f2bf(v - bf2f(hi)) : hi;
}

__global__ void k_wprep_all(
    const float* eW0, const float* eW1, const float* projW,
    const float* g0Wx, const float* g0Wh, const float* g1Wx, const float* g1Wh,
    unsigned short* eW0f, unsigned short* eW1f, unsigned short* projf,
    unsigned short* g0xf, unsigned short* g0hf,
    unsigned short* g1xf, unsigned short* g1hf) {
  int rel = blockIdx.x * 256 + threadIdx.x;
  if (rel < 65536) { wprep_one(eW0, eW0f, 64, 64, rel); return; }
  rel -= 65536;
  if (rel < 65536) { wprep_one(eW1, eW1f, 64, 64, rel); return; }
  rel -= 65536;
  if (rel < 8192)  { wprep_one(projW, projf, 64, 64, rel); return; }
  rel -= 8192;
  if (rel < 24576) { wprep_one(g0Wx, g0xf, 64, 192, rel); return; }
  rel -= 24576;
  if (rel < 24576) { wprep_one(g0Wh, g0hf, 64, 192, rel); return; }
  rel -= 24576;
  if (rel < 49152) { wprep_one(g1Wx, g1xf, 128, 192, rel); return; }
  rel -= 49152;
  if (rel < 24576) { wprep_one(g1Wh, g1hf, 64, 192, rel); return; }
}

// ---------- embedding gather (coalesced: 64 lanes = 64 features) ----------
__global__ __launch_bounds__(256) void k_embed(
    const int* __restrict__ toks, const float* __restrict__ embed,
    unsigned short* __restrict__ eh, unsigned short* __restrict__ el, int N) {
  int w = threadIdx.x >> 6, lane = threadIdx.x & 63;
  int n = blockIdx.x * 4 + w;
  if (n >= N) return;
  float acc = 0.f;
#pragma unroll
  for (int s = 0; s < 5; ++s)
    acc += embed[(size_t)toks[n * 5 + s] * 64 + lane];
  float v = acc * 0.2f;
  unsigned short h = f2bf(v);
  eh[(size_t)n * 64 + lane] = h;
  el[(size_t)n * 64 + lane] = f2bf(v - bf2f(h));
}

// ---------- CSR build: each thread handles fwd+bwd of one edge ----------
__global__ void k_counts(const int* __restrict__ adj, int* __restrict__ counts, int E) {
  int e = blockIdx.x * 256 + threadIdx.x;
  if (e >= E) return;
  int t4 = blockIdx.y;
  int2 ab = *(const int2*)&adj[(size_t)(t4 * E + e) * 2];
  atomicAdd(&counts[ab.y], 1);
  atomicAdd(&counts[ab.x], 1);
}

__global__ __launch_bounds__(1024) void k_scan(const int* __restrict__ counts,
                                               int* __restrict__ offsets,
                                               int* __restrict__ cursor, int n) {
  __shared__ int part[1024];
  int tid = threadIdx.x;
  int chunk = (((n + 1023) >> 10) + 3) & ~3;
  int begin = tid * chunk;
  int end = min(begin + chunk, n);
  int s = 0;
  int i = begin;
  for (; i + 4 <= end; i += 4) {
    int4 v = *(const int4*)&counts[i];
    s += v.x + v.y + v.z + v.w;
  }
  for (; i < end; ++i) s += counts[i];
  part[tid] = s;
  __syncthreads();
  for (int off = 1; off < 1024; off <<= 1) {
    int v = (tid >= off) ? part[tid - off] : 0;
    __syncthreads();
    part[tid] += v;
    __syncthreads();
  }
  int run = part[tid] - s;
  i = begin;
  for (; i + 4 <= end; i += 4) {
    int4 c = *(const int4*)&counts[i];
    int4 o;
    o.x = run; o.y = run + c.x; o.z = o.y + c.y; o.w = o.z + c.z;
    *(int4*)&offsets[i] = o;
    *(int4*)&cursor[i] = o;
    run = o.w + c.w;
  }
  for (; i < end; ++i) {
    offsets[i] = run; cursor[i] = run; run += counts[i];
  }
  if (tid == 1023) offsets[n] = part[1023];
}

__global__ void k_fill(const int* __restrict__ adj, int* __restrict__ cursor,
                       int* __restrict__ entries, int E, int N) {
  int e = blockIdx.x * 256 + threadIdx.x;
  if (e >= E) return;
  int t4 = blockIdx.y;
  int2 ab = *(const int2*)&adj[(size_t)(t4 * E + e) * 2];
  int p1 = atomicAdd(&cursor[ab.y], 1);
  entries[p1] = t4 * N + ab.x;
  int p2 = atomicAdd(&cursor[ab.x], 1);
  entries[p2] = (t4 + 4) * N + ab.y;
}

// ---------- proj GEMM: h_init = emb @ projW ----------
__global__ __launch_bounds__(256) void k_proj(
    const unsigned short* __restrict__ A0h, const unsigned short* __restrict__ A0l,
    const unsigned short* __restrict__ Wf,
    unsigned short* __restrict__ h_hi, unsigned short* __restrict__ h_lo,
    unsigned short* __restrict__ hinit_b, int N) {
  int tid = threadIdx.x;
  int wv = tid >> 6, lane = tid & 63;
  int lr = lane & 15, lg = lane >> 4;
  int m0 = blockIdx.x * 128 + wv * 32;
  v4f acc[2][4] = {};
#pragma unroll
  for (int kc = 0; kc < 2; ++kc) {
    v8s ah[2], al[2];
#pragma unroll
    for (int mt = 0; mt < 2; ++mt) {
      int row = min(m0 + mt * 16 + lr, N - 1);
      size_t off = (size_t)row * 64 + kc * 32 + lg * 8;
      ah[mt] = *(const v8s*)&A0h[off];
      al[mt] = *(const v8s*)&A0l[off];
    }
#pragma unroll
    for (int ct = 0; ct < 4; ++ct) {
      v8s bh = *(const v8s*)&Wf[((size_t)(kc * 4 + ct)) * 512 + lane * 8];
      v8s bl = *(const v8s*)&Wf[((size_t)((2 + kc) * 4 + ct)) * 512 + lane * 8];
#pragma unroll
      for (int mt = 0; mt < 2; ++mt) {
        acc[mt][ct] = __builtin_amdgcn_mfma_f32_16x16x32_bf16(ah[mt], bh, acc[mt][ct], 0, 0, 0);
        acc[mt][ct] = __builtin_amdgcn_mfma_f32_16x16x32_bf16(al[mt], bh, acc[mt][ct], 0, 0, 0);
        acc[mt][ct] = __builtin_amdgcn_mfma_f32_16x16x32_bf16(ah[mt], bl, acc[mt][ct], 0, 0, 0);
      }
    }
  }
#pragma unroll
  for (int ct = 0; ct < 4; ++ct)
#pragma unroll
    for (int mt = 0; mt < 2; ++mt)
#pragma unroll
      for (int r = 0; r < 4; ++r) {
        int m = m0 + mt * 16 + lg * 4 + r;
        if (m >= N) continue;
        int col = ct * 16 + lr;
        float v = acc[mt][ct][r];
        unsigned short hb = f2bf(v);
        h_hi[(size_t)m * 64 + col] = hb;
        h_lo[(size_t)m * 64 + col] = f2bf(v - bf2f(hb));
        hinit_b[(size_t)m * 64 + col] = hb;
      }
}

// ---------- initial transform: Ht[t][n] = h[n] @ W[t], 2 types per block ----------
__global__ __launch_bounds__(256) void k_mm_t(
    const unsigned short* __restrict__ A0h, const unsigned short* __restrict__ A0l,
    const unsigned short* __restrict__ Wf, unsigned short* __restrict__ C16,
    int N) {
  int tid = threadIdx.x;
  int wv = tid >> 6, lane = tid & 63;
  int lr = lane & 15, lg = lane >> 4;
  int y = blockIdx.y;
  const unsigned short* W0 = Wf + (size_t)y * 8192;
  const unsigned short* W1 = Wf + (size_t)(y + 4) * 8192;
  unsigned short* C0 = C16 + (size_t)y * N * 64;
  unsigned short* C1 = C16 + (size_t)(y + 4) * N * 64;
  int m0 = blockIdx.x * 128 + wv * 32;
  v4f acc0[2][4] = {}, acc1[2][4] = {};
#pragma unroll
  for (int kc = 0; kc < 2; ++kc) {
    v8s ah[2], al[2];
#pragma unroll
    for (int mt = 0; mt < 2; ++mt) {
      int row = min(m0 + mt * 16 + lr, N - 1);
      size_t off = (size_t)row * 64 + kc * 32 + lg * 8;
      ah[mt] = *(const v8s*)&A0h[off];
      al[mt] = *(const v8s*)&A0l[off];
    }
#pragma unroll
    for (int ct = 0; ct < 4; ++ct) {
      v8s bh0 = *(const v8s*)&W0[((size_t)(kc * 4 + ct)) * 512 + lane * 8];
      v8s bl0 = *(const v8s*)&W0[((size_t)((2 + kc) * 4 + ct)) * 512 + lane * 8];
      v8s bh1 = *(const v8s*)&W1[((size_t)(kc * 4 + ct)) * 512 + lane * 8];
      v8s bl1 = *(const v8s*)&W1[((size_t)((2 + kc) * 4 + ct)) * 512 + lane * 8];
#pragma unroll
      for (int mt = 0; mt < 2; ++mt) {
        acc0[mt][ct] = __builtin_amdgcn_mfma_f32_16x16x32_bf16(ah[mt], bh0, acc0[mt][ct], 0, 0, 0);
        acc0[mt][ct] = __builtin_amdgcn_mfma_f32_16x16x32_bf16(al[mt], bh0, acc0[mt][ct], 0, 0, 0);
        acc0[mt][ct] = __builtin_amdgcn_mfma_f32_16x16x32_bf16(ah[mt], bl0, acc0[mt][ct], 0, 0, 0);
        acc1[mt][ct] = __builtin_amdgcn_mfma_f32_16x16x32_bf16(ah[mt], bh1, acc1[mt][ct], 0, 0, 0);
        acc1[mt][ct] = __builtin_amdgcn_mfma_f32_16x16x32_bf16(al[mt], bh1, acc1[mt][ct], 0, 0, 0);
        acc1[mt][ct] = __builtin_amdgcn_mfma_f32_16x16x32_bf16(ah[mt], bl1, acc1[mt][ct], 0, 0, 0);
      }
    }
  }
#pragma unroll
  for (int ct = 0; ct < 4; ++ct)
#pragma unroll
    for (int mt = 0; mt < 2; ++mt)
#pragma unroll
      for (int r = 0; r < 4; ++r) {
        int m = m0 + mt * 16 + lg * 4 + r;
        if (m < N) {
          C0[(size_t)m * 64 + ct * 16 + lr] = f2bf(acc0[mt][ct][r]);
          C1[(size_t)m * 64 + ct * 16 + lr] = f2bf(acc1[mt][ct][r]);
        }
      }
}

// ---------- segment-max: big-grid latency-bound gather (1 wave = 1 node) ----------
__global__ __launch_bounds__(256) void k_aggmax(
    const unsigned short* __restrict__ Htb, const int* __restrict__ offsets,
    const int* __restrict__ entries, unsigned short* __restrict__ mh, int N) {
  int w = threadIdx.x >> 6, lane = threadIdx.x & 63;
  int n = blockIdx.x * 4 + w;
  if (n >= N) return;
  int beg = offsets[n], end = offsets[n + 1];
  int g = lane >> 4, q = lane & 15;
  float a0 = -3.4e38f, a1 = a0, a2 = a0, a3 = a0;
  float b0 = a0, b1 = a0, b2 = a0, b3 = a0;
  int i = beg;
  for (; i + 8 <= end; i += 8) {
    int eA = entries[i + g];
    int eB = entries[i + 4 + g];
    ushort4 va = *(const ushort4*)&Htb[(size_t)eA * 64 + q * 4];
    ushort4 vb = *(const ushort4*)&Htb[(size_t)eB * 64 + q * 4];
    a0 = fmaxf(a0, bf2f(va.x)); a1 = fmaxf(a1, bf2f(va.y));
    a2 = fmaxf(a2, bf2f(va.z)); a3 = fmaxf(a3, bf2f(va.w));
    b0 = fmaxf(b0, bf2f(vb.x)); b1 = fmaxf(b1, bf2f(vb.y));
    b2 = fmaxf(b2, bf2f(vb.z)); b3 = fmaxf(b3, bf2f(vb.w));
  }
  for (; i < end; i += 4) {
    int idx = min(i + g, end - 1);  // clamped dup loads harmless for max
    int e = entries[idx];
    ushort4 va = *(const ushort4*)&Htb[(size_t)e * 64 + q * 4];
    a0 = fmaxf(a0, bf2f(va.x)); a1 = fmaxf(a1, bf2f(va.y));
    a2 = fmaxf(a2, bf2f(va.z)); a3 = fmaxf(a3, bf2f(va.w));
  }
  a0 = fmaxf(a0, b0); a1 = fmaxf(a1, b1); a2 = fmaxf(a2, b2); a3 = fmaxf(a3, b3);
  a0 = fmaxf(a0, __shfl_xor(a0, 16)); a1 = fmaxf(a1, __shfl_xor(a1, 16));
  a2 = fmaxf(a2, __shfl_xor(a2, 16)); a3 = fmaxf(a3, __shfl_xor(a3, 16));
  a0 = fmaxf(a0, __shfl_xor(a0, 32)); a1 = fmaxf(a1, __shfl_xor(a1, 32));
  a2 = fmaxf(a2, __shfl_xor(a2, 32)); a3 = fmaxf(a3, __shfl_xor(a3, 32));
  if (g == 0) {
    ushort4 o;
    if (end > beg) {
      o.x = f2bf(a0); o.y = f2bf(a1); o.z = f2bf(a2); o.w = f2bf(a3);
    } else {
      o.x = 0; o.y = 0; o.z = 0; o.w = 0;
    }
    *(ushort4*)&mh[(size_t)n * 64 + q * 4] = o;
  }
}

// ---------- fused GRU + next-step transform (same grid, same tile) ----------
// FINAL=0: gru0 (x=msg global), write h, stage new h in LDS, transform -> HtW.
// FINAL=1: gru1 (x=concat(hinit, msg)), write f32 out; no transform.
// All LDS rows are wave-local -> NO __syncthreads.
template <int FINAL>
__global__ __launch_bounds__(256) void k_gt(
    const unsigned short* __restrict__ x0, const unsigned short* __restrict__ x1,
    unsigned short* __restrict__ hh, unsigned short* __restrict__ hl,
    const unsigned short* __restrict__ Wxf, const unsigned short* __restrict__ Whf,
    const float* __restrict__ bias, const unsigned short* __restrict__ eWf,
    unsigned short* __restrict__ HtW, float* __restrict__ outF, int N) {
  __shared__ __align__(16) char lds_hs[FINAL ? 16 : 2 * 128 * 128]; // 32 KB
  int tid = threadIdx.x;
  int wv = tid >> 6, lane = tid & 63;
  int lr = lane & 15, lg = lane >> 4;
  int lbase = wv * 32;
  int m0 = blockIdx.x * 128 + lbase;

  const int NKCX = FINAL ? 4 : 2;
  v4f acc[2][12] = {};   // xr,xu,xc (+hr,hu merged)
  v4f acch[2][4] = {};   // hc separate
#pragma unroll
  for (int kc = 0; kc < NKCX; ++kc) {
    const unsigned short* X = (FINAL && kc >= 2) ? x1 : x0;
    int kcl = kc & 1;
    v8s ax[2];
#pragma unroll
    for (int mt = 0; mt < 2; ++mt) {
      int row = min(m0 + mt * 16 + lr, N - 1);
      ax[mt] = *(const v8s*)&X[(size_t)row * 64 + kcl * 32 + lg * 8];
    }
#pragma unroll
    for (int ct = 0; ct < 12; ++ct) {
      v8s bh = *(const v8s*)&Wxf[((size_t)(kc * 12 + ct)) * 512 + lane * 8];
      v8s bl = *(const v8s*)&Wxf[((size_t)((NKCX + kc) * 12 + ct)) * 512 + lane * 8];
#pragma unroll
      for (int mt = 0; mt < 2; ++mt) {
        acc[mt][ct] = __builtin_amdgcn_mfma_f32_16x16x32_bf16(ax[mt], bh, acc[mt][ct], 0, 0, 0);
        acc[mt][ct] = __builtin_amdgcn_mfma_f32_16x16x32_bf16(ax[mt], bl, acc[mt][ct], 0, 0, 0);
      }
    }
  }
#pragma unroll
  for (int kc = 0; kc < 2; ++kc) {
    v8s ah[2], al[2];
#pragma unroll
    for (int mt = 0; mt < 2; ++mt) {
      int row = min(m0 + mt * 16 + lr, N - 1);
      size_t off = (size_t)row * 64 + kc * 32 + lg * 8;
      ah[mt] = *(const v8s*)&hh[off];
      al[mt] = *(const v8s*)&hl[off];
    }
#pragma unroll
    for (int ct = 0; ct < 12; ++ct) {
      v8s bh = *(const v8s*)&Whf[((size_t)(kc * 12 + ct)) * 512 + lane * 8];
      v8s bl = *(const v8s*)&Whf[((size_t)((2 + kc) * 12 + ct)) * 512 + lane * 8];
#pragma unroll
      for (int mt = 0; mt < 2; ++mt) {
        v4f* d = (ct < 8) ? &acc[mt][ct] : &acch[mt][ct - 8];
        *d = __builtin_amdgcn_mfma_f32_16x16x32_bf16(ah[mt], bh, *d, 0, 0, 0);
        *d = __builtin_amdgcn_mfma_f32_16x16x32_bf16(al[mt], bh, *d, 0, 0, 0);
        *d = __builtin_amdgcn_mfma_f32_16x16x32_bf16(ah[mt], bl, *d, 0, 0, 0);
      }
    }
  }
  // gate epilogue
#pragma unroll
  for (int mt = 0; mt < 2; ++mt)
#pragma unroll
    for (int ctg = 0; ctg < 4; ++ctg)
#pragma unroll
      for (int r = 0; r < 4; ++r) {
        int m = m0 + mt * 16 + lg * 4 + r;
        int col = ctg * 16 + lr;
        unsigned short hbv = hh[(size_t)min(m, N - 1) * 64 + col];
        unsigned short hlv = hl[(size_t)min(m, N - 1) * 64 + col];
        float hv = bf2f(hbv) + bf2f(hlv);
        float rr = sigmoidf_(acc[mt][ctg][r] + bias[col]);
        float uu = sigmoidf_(acc[mt][ctg + 4][r] + bias[64 + col]);
        float cc = tanhf_(acc[mt][ctg + 8][r] + bias[128 + col] + rr * acch[mt][ctg][r]);
        float ho = uu * hv + (1.f - uu) * cc;
        if (FINAL) {
          if (m < N) outF[(size_t)m * 64 + col] = ho;
        } else {
          unsigned short ohi = f2bf(ho);
          unsigned short olo = f2bf(ho - bf2f(ohi));
          if (m < N) {
            hh[(size_t)m * 64 + col] = ohi;
            hl[(size_t)m * 64 + col] = olo;
          }
          int row = lbase + mt * 16 + lg * 4 + r;
          *(unsigned short*)(lds_hs + swz(row, col * 2)) = ohi;
          *(unsigned short*)(lds_hs + 128 * 128 + swz(row, col * 2)) = olo;
        }
      }

  if (FINAL) return;

  // ---- transform new h -> HtW for all 8 types (2 per pass) ----
  v8s tah[2][2], tal[2][2];  // [kc][mt]
#pragma unroll
  for (int kc = 0; kc < 2; ++kc)
#pragma unroll
    for (int mt = 0; mt < 2; ++mt) {
      int row = lbase + mt * 16 + lr;
      tah[kc][mt] = *(const v8s*)(lds_hs + swz(row, kc * 64 + lg * 16));
      tal[kc][mt] = *(const v8s*)(lds_hs + 128 * 128 + swz(row, kc * 64 + lg * 16));
    }
#pragma unroll
  for (int y = 0; y < 4; ++y) {
    const unsigned short* W0 = eWf + (size_t)y * 8192;
    const unsigned short* W1 = eWf + (size_t)(y + 4) * 8192;
    unsigned short* C0 = HtW + (size_t)y * N * 64;
    unsigned short* C1 = HtW + (size_t)(y + 4) * N * 64;
    v4f acc0[2][4] = {}, acc1[2][4] = {};
#pragma unroll
    for (int kc = 0; kc < 2; ++kc)
#pragma unroll
      for (int ct = 0; ct < 4; ++ct) {
        v8s bh0 = *(const v8s*)&W0[((size_t)(kc * 4 + ct)) * 512 + lane * 8];
        v8s bl0 = *(const v8s*)&W0[((size_t)((2 + kc) * 4 + ct)) * 512 + lane * 8];
        v8s bh1 = *(const v8s*)&W1[((size_t)(kc * 4 + ct)) * 512 + lane * 8];
        v8s bl1 = *(const v8s*)&W1[((size_t)((2 + kc) * 4 + ct)) * 512 + lane * 8];
#pragma unroll
        for (int mt = 0; mt < 2; ++mt) {
          acc0[mt][ct] = __builtin_amdgcn_mfma_f32_16x16x32_bf16(tah[kc][mt], bh0, acc0[mt][ct], 0, 0, 0);
          acc0[mt][ct] = __builtin_amdgcn_mfma_f32_16x16x32_bf16(tal[kc][mt], bh0, acc0[mt][ct], 0, 0, 0);
          acc0[mt][ct] = __builtin_amdgcn_mfma_f32_16x16x32_bf16(tah[kc][mt], bl0, acc0[mt][ct], 0, 0, 0);
          acc1[mt][ct] = __builtin_amdgcn_mfma_f32_16x16x32_bf16(tah[kc][mt], bh1, acc1[mt][ct], 0, 0, 0);
          acc1[mt][ct] = __builtin_amdgcn_mfma_f32_16x16x32_bf16(tal[kc][mt], bh1, acc1[mt][ct], 0, 0, 0);
          acc1[mt][ct] = __builtin_amdgcn_mfma_f32_16x16x32_bf16(tah[kc][mt], bl1, acc1[mt][ct], 0, 0, 0);
        }
      }
#pragma unroll
    for (int ct = 0; ct < 4; ++ct)
#pragma unroll
      for (int mt = 0; mt < 2; ++mt)
#pragma unroll
        for (int r = 0; r < 4; ++r) {
          int m = m0 + mt * 16 + lg * 4 + r;
          if (m < N) {
            C0[(size_t)m * 64 + ct * 16 + lr] = f2bf(acc0[mt][ct][r]);
            C1[(size_t)m * 64 + ct * 16 + lr] = f2bf(acc1[mt][ct][r]);
          }
        }
  }
}

extern "C" void kernel_launch(void* const* d_in, const int* in_sizes, int n_in,
                              void* d_out, int out_size, void* d_ws, size_t ws_size,
                              hipStream_t stream) {
  const int*   toks  = (const int*)d_in[0];
  const int*   adj   = (const int*)d_in[1];
  const float* embed = (const float*)d_in[2];
  const float* projW = (const float*)d_in[3];
  const float* eW0   = (const float*)d_in[4];
  const float* eW1   = (const float*)d_in[5];
  const float* g0Wx  = (const float*)d_in[6];
  const float* g0Wh  = (const float*)d_in[7];
  const float* g0b   = (const float*)d_in[8];
  const float* g1Wx  = (const float*)d_in[9];
  const float* g1Wh  = (const float*)d_in[10];
  const float* g1b   = (const float*)d_in[11];
  float* out = (float*)d_out;

  int N = in_sizes[0] / 5;
  int E = in_sizes[1] / 8;
  size_t ND = (size_t)N * 64;

  char* p = (char*)d_ws;
  unsigned short* Htb     = (unsigned short*)p; p += 8 * ND * 2;   // 61.4 MB
  unsigned short* h_hi    = (unsigned short*)p; p += ND * 2;
  unsigned short* h_lo    = (unsigned short*)p; p += ND * 2;
  unsigned short* hinit_b = (unsigned short*)p; p += ND * 2;
  unsigned short* m_hi    = (unsigned short*)p; p += ND * 2;
  int* offsets = (int*)p; p += (size_t)(N + 64) * sizeof(int);
  int* cnt_cur = (int*)p; p += (size_t)(N + 64) * sizeof(int);
  int* entries = (int*)p; p += (size_t)8 * E * sizeof(int);
  unsigned short* eW0f  = (unsigned short*)p; p += 65536 * 2;
  unsigned short* eW1f  = (unsigned short*)p; p += 65536 * 2;
  unsigned short* projf = (unsigned short*)p; p += 8192 * 2;
  unsigned short* g0xf  = (unsigned short*)p; p += 24576 * 2;
  unsigned short* g0hf  = (unsigned short*)p; p += 24576 * 2;
  unsigned short* g1xf  = (unsigned short*)p; p += 49152 * 2;
  unsigned short* g1hf  = (unsigned short*)p; p += 24576 * 2;
  if ((size_t)(p - (char*)d_ws) > ws_size) return;

  // init-phase aliases inside Htb (consumed by k_proj before k_mm_t writes Htb)
  unsigned short* emb_h = Htb;
  unsigned short* emb_l = Htb + ND;

  int g128 = (N + 127) / 128;
  int g4 = (N + 3) / 4;

  k_wprep_all<<<1024, 256, 0, stream>>>(eW0, eW1, projW, g0Wx, g0Wh, g1Wx, g1Wh,
                                        eW0f, eW1f, projf, g0xf, g0hf, g1xf, g1hf);
  hipMemsetAsync(cnt_cur, 0, (size_t)N * sizeof(int), stream);
  dim3 egrid((E + 255) / 256, 4);
  k_counts<<<egrid, 256, 0, stream>>>(adj, cnt_cur, E);
  k_embed<<<g4, 256, 0, stream>>>(toks, embed, emb_h, emb_l, N);
  k_proj<<<g128, 256, 0, stream>>>(emb_h, emb_l, projf, h_hi, h_lo, hinit_b, N);
  k_scan<<<1, 1024, 0, stream>>>(cnt_cur, offsets, cnt_cur, N);
  k_fill<<<egrid, 256, 0, stream>>>(adj, cnt_cur, entries, E, N);
  // initial transform (step-0 messages): h_init -> Htb with eW0
  k_mm_t<<<dim3(g128, 4), 256, 0, stream>>>(h_hi, h_lo, eW0f, Htb, N);

  for (int it = 0; it < 7; ++it) {
    k_aggmax<<<g4, 256, 0, stream>>>(Htb, offsets, entries, m_hi, N);
    // gru0 + transform of the NEW h for step it+1 (eW1 when it+1 == 7)
    const unsigned short* ef = (it < 6) ? eW0f : eW1f;
    k_gt<0><<<g128, 256, 0, stream>>>(m_hi, nullptr, h_hi, h_lo,
                                      g0xf, g0hf, g0b, ef, Htb, nullptr, N);
  }
  k_aggmax<<<g4, 256, 0, stream>>>(Htb, offsets, entries, m_hi, N);
  k_gt<1><<<g128, 256, 0, stream>>>(hinit_b, m_hi, h_hi, h_lo,
                                    g1xf, g1hf, g1b, nullptr, nullptr, out, N);
}

// Round 10
// 1089.261 us; speedup vs baseline: 1.1256x; 1.0221x over previous
//
#include <hip/hip_runtime.h>

typedef short v8s __attribute__((ext_vector_type(8)));
typedef float v4f __attribute__((ext_vector_type(4)));

__device__ __forceinline__ unsigned short f2bf(float x) {
  unsigned u = __float_as_uint(x);
  u = u + 0x7FFFu + ((u >> 16) & 1u);
  return (unsigned short)(u >> 16);
}
__device__ __forceinline__ float bf2f(unsigned short b) {
  return __uint_as_float(((unsigned)b) << 16);
}
__device__ __forceinline__ float sigmoidf_(float x) {
  return 1.f / (1.f + __expf(-x));
}
__device__ __forceinline__ float tanhf_(float x) {
  x = fminf(fmaxf(x, -20.f), 20.f);
  float e2 = __expf(2.f * x);
  return (e2 - 1.f) / (e2 + 1.f);
}
// LDS swizzle: XOR byte-bits 4-6 with row&7 (rows are 128 B) -> 2-way max.
__device__ __forceinline__ int swz(int row, int byteInRow) {
  return row * 128 + (byteInRow ^ ((row & 7) << 4));
}

// ---------- merged weight prep ----------
// frag layout per weight: idx = ((p*nkc + kc)*nct + ct)*512 + lane*8 + j
// value: W[t][kc*32+(lane>>4)*8+j][ct*16+(lane&15)], p=0 hi, p=1 lo.
__device__ __forceinline__ void wprep_one(const float* W, unsigned short* O,
                                          int K, int J, int idx) {
  int nkc = K >> 5, nct = J >> 4;
  int j = idx & 7, lane = (idx >> 3) & 63;
  int rest = idx >> 9;
  int ct = rest % nct; rest /= nct;
  int kc = rest % nkc; rest /= nkc;
  int p = rest & 1, t = rest >> 1;
  int row = kc * 32 + (lane >> 4) * 8 + j;
  int col = ct * 16 + (lane & 15);
  float v = W[(size_t)t * K * J + (size_t)row * J + col];
  unsigned short hi = f2bf(v);
  O[idx] = p ? f2bf(v - bf2f(hi)) : hi;
}

__global__ void k_wprep_all(
    const float* eW0, const float* eW1, const float* projW,
    const float* g0Wx, const float* g0Wh, const float* g1Wx, const float* g1Wh,
    unsigned short* eW0f, unsigned short* eW1f, unsigned short* projf,
    unsigned short* g0xf, unsigned short* g0hf,
    unsigned short* g1xf, unsigned short* g1hf) {
  int rel = blockIdx.x * 256 + threadIdx.x;
  if (rel < 65536) { wprep_one(eW0, eW0f, 64, 64, rel); return; }
  rel -= 65536;
  if (rel < 65536) { wprep_one(eW1, eW1f, 64, 64, rel); return; }
  rel -= 65536;
  if (rel < 8192)  { wprep_one(projW, projf, 64, 64, rel); return; }
  rel -= 8192;
  if (rel < 24576) { wprep_one(g0Wx, g0xf, 64, 192, rel); return; }
  rel -= 24576;
  if (rel < 24576) { wprep_one(g0Wh, g0hf, 64, 192, rel); return; }
  rel -= 24576;
  if (rel < 49152) { wprep_one(g1Wx, g1xf, 128, 192, rel); return; }
  rel -= 49152;
  if (rel < 24576) { wprep_one(g1Wh, g1hf, 64, 192, rel); return; }
}

// ---------- embedding gather (coalesced: 64 lanes = 64 features) ----------
__global__ __launch_bounds__(256) void k_embed(
    const int* __restrict__ toks, const float* __restrict__ embed,
    unsigned short* __restrict__ eh, unsigned short* __restrict__ el, int N) {
  int w = threadIdx.x >> 6, lane = threadIdx.x & 63;
  int n = blockIdx.x * 4 + w;
  if (n >= N) return;
  float acc = 0.f;
#pragma unroll
  for (int s = 0; s < 5; ++s)
    acc += embed[(size_t)toks[n * 5 + s] * 64 + lane];
  float v = acc * 0.2f;
  unsigned short h = f2bf(v);
  eh[(size_t)n * 64 + lane] = h;
  el[(size_t)n * 64 + lane] = f2bf(v - bf2f(h));
}

// ---------- CSR build: each thread handles fwd+bwd of one edge ----------
__global__ void k_counts(const int* __restrict__ adj, int* __restrict__ counts, int E) {
  int e = blockIdx.x * 256 + threadIdx.x;
  if (e >= E) return;
  int t4 = blockIdx.y;
  int2 ab = *(const int2*)&adj[(size_t)(t4 * E + e) * 2];
  atomicAdd(&counts[ab.y], 1);
  atomicAdd(&counts[ab.x], 1);
}

__global__ __launch_bounds__(1024) void k_scan(const int* __restrict__ counts,
                                               int* __restrict__ offsets,
                                               int* __restrict__ cursor, int n) {
  __shared__ int part[1024];
  int tid = threadIdx.x;
  int chunk = (((n + 1023) >> 10) + 3) & ~3;
  int begin = tid * chunk;
  int end = min(begin + chunk, n);
  int s = 0;
  int i = begin;
  for (; i + 4 <= end; i += 4) {
    int4 v = *(const int4*)&counts[i];
    s += v.x + v.y + v.z + v.w;
  }
  for (; i < end; ++i) s += counts[i];
  part[tid] = s;
  __syncthreads();
  for (int off = 1; off < 1024; off <<= 1) {
    int v = (tid >= off) ? part[tid - off] : 0;
    __syncthreads();
    part[tid] += v;
    __syncthreads();
  }
  int run = part[tid] - s;
  i = begin;
  for (; i + 4 <= end; i += 4) {
    int4 c = *(const int4*)&counts[i];
    int4 o;
    o.x = run; o.y = run + c.x; o.z = o.y + c.y; o.w = o.z + c.z;
    *(int4*)&offsets[i] = o;
    *(int4*)&cursor[i] = o;
    run = o.w + c.w;
  }
  for (; i < end; ++i) {
    offsets[i] = run; cursor[i] = run; run += counts[i];
  }
  if (tid == 1023) offsets[n] = part[1023];
}

__global__ void k_fill(const int* __restrict__ adj, int* __restrict__ cursor,
                       int* __restrict__ entries, int E, int N) {
  int e = blockIdx.x * 256 + threadIdx.x;
  if (e >= E) return;
  int t4 = blockIdx.y;
  int2 ab = *(const int2*)&adj[(size_t)(t4 * E + e) * 2];
  int p1 = atomicAdd(&cursor[ab.y], 1);
  entries[p1] = t4 * N + ab.x;
  int p2 = atomicAdd(&cursor[ab.x], 1);
  entries[p2] = (t4 + 4) * N + ab.y;
}

// ---------- proj GEMM: h_init = emb @ projW ----------
__global__ __launch_bounds__(256) void k_proj(
    const unsigned short* __restrict__ A0h, const unsigned short* __restrict__ A0l,
    const unsigned short* __restrict__ Wf,
    unsigned short* __restrict__ h_hi, unsigned short* __restrict__ h_lo,
    unsigned short* __restrict__ hinit_b, int N) {
  int tid = threadIdx.x;
  int wv = tid >> 6, lane = tid & 63;
  int lr = lane & 15, lg = lane >> 4;
  int m0 = blockIdx.x * 128 + wv * 32;
  v4f acc[2][4] = {};
#pragma unroll
  for (int kc = 0; kc < 2; ++kc) {
    v8s ah[2], al[2];
#pragma unroll
    for (int mt = 0; mt < 2; ++mt) {
      int row = min(m0 + mt * 16 + lr, N - 1);
      size_t off = (size_t)row * 64 + kc * 32 + lg * 8;
      ah[mt] = *(const v8s*)&A0h[off];
      al[mt] = *(const v8s*)&A0l[off];
    }
#pragma unroll
    for (int ct = 0; ct < 4; ++ct) {
      v8s bh = *(const v8s*)&Wf[((size_t)(kc * 4 + ct)) * 512 + lane * 8];
      v8s bl = *(const v8s*)&Wf[((size_t)((2 + kc) * 4 + ct)) * 512 + lane * 8];
#pragma unroll
      for (int mt = 0; mt < 2; ++mt) {
        acc[mt][ct] = __builtin_amdgcn_mfma_f32_16x16x32_bf16(ah[mt], bh, acc[mt][ct], 0, 0, 0);
        acc[mt][ct] = __builtin_amdgcn_mfma_f32_16x16x32_bf16(al[mt], bh, acc[mt][ct], 0, 0, 0);
        acc[mt][ct] = __builtin_amdgcn_mfma_f32_16x16x32_bf16(ah[mt], bl, acc[mt][ct], 0, 0, 0);
      }
    }
  }
#pragma unroll
  for (int ct = 0; ct < 4; ++ct)
#pragma unroll
    for (int mt = 0; mt < 2; ++mt)
#pragma unroll
      for (int r = 0; r < 4; ++r) {
        int m = m0 + mt * 16 + lg * 4 + r;
        if (m >= N) continue;
        int col = ct * 16 + lr;
        float v = acc[mt][ct][r];
        unsigned short hb = f2bf(v);
        h_hi[(size_t)m * 64 + col] = hb;
        h_lo[(size_t)m * 64 + col] = f2bf(v - bf2f(hb));
        hinit_b[(size_t)m * 64 + col] = hb;
      }
}

// ---------- initial transform: Ht[t][n] = h[n] @ W[t], 2 types per block ----------
__global__ __launch_bounds__(256) void k_mm_t(
    const unsigned short* __restrict__ A0h, const unsigned short* __restrict__ A0l,
    const unsigned short* __restrict__ Wf, unsigned short* __restrict__ C16,
    int N) {
  int tid = threadIdx.x;
  int wv = tid >> 6, lane = tid & 63;
  int lr = lane & 15, lg = lane >> 4;
  int y = blockIdx.y;
  const unsigned short* W0 = Wf + (size_t)y * 8192;
  const unsigned short* W1 = Wf + (size_t)(y + 4) * 8192;
  unsigned short* C0 = C16 + (size_t)y * N * 64;
  unsigned short* C1 = C16 + (size_t)(y + 4) * N * 64;
  int m0 = blockIdx.x * 128 + wv * 32;
  v4f acc0[2][4] = {}, acc1[2][4] = {};
#pragma unroll
  for (int kc = 0; kc < 2; ++kc) {
    v8s ah[2], al[2];
#pragma unroll
    for (int mt = 0; mt < 2; ++mt) {
      int row = min(m0 + mt * 16 + lr, N - 1);
      size_t off = (size_t)row * 64 + kc * 32 + lg * 8;
      ah[mt] = *(const v8s*)&A0h[off];
      al[mt] = *(const v8s*)&A0l[off];
    }
#pragma unroll
    for (int ct = 0; ct < 4; ++ct) {
      v8s bh0 = *(const v8s*)&W0[((size_t)(kc * 4 + ct)) * 512 + lane * 8];
      v8s bl0 = *(const v8s*)&W0[((size_t)((2 + kc) * 4 + ct)) * 512 + lane * 8];
      v8s bh1 = *(const v8s*)&W1[((size_t)(kc * 4 + ct)) * 512 + lane * 8];
      v8s bl1 = *(const v8s*)&W1[((size_t)((2 + kc) * 4 + ct)) * 512 + lane * 8];
#pragma unroll
      for (int mt = 0; mt < 2; ++mt) {
        acc0[mt][ct] = __builtin_amdgcn_mfma_f32_16x16x32_bf16(ah[mt], bh0, acc0[mt][ct], 0, 0, 0);
        acc0[mt][ct] = __builtin_amdgcn_mfma_f32_16x16x32_bf16(al[mt], bh0, acc0[mt][ct], 0, 0, 0);
        acc0[mt][ct] = __builtin_amdgcn_mfma_f32_16x16x32_bf16(ah[mt], bl0, acc0[mt][ct], 0, 0, 0);
        acc1[mt][ct] = __builtin_amdgcn_mfma_f32_16x16x32_bf16(ah[mt], bh1, acc1[mt][ct], 0, 0, 0);
        acc1[mt][ct] = __builtin_amdgcn_mfma_f32_16x16x32_bf16(al[mt], bh1, acc1[mt][ct], 0, 0, 0);
        acc1[mt][ct] = __builtin_amdgcn_mfma_f32_16x16x32_bf16(ah[mt], bl1, acc1[mt][ct], 0, 0, 0);
      }
    }
  }
#pragma unroll
  for (int ct = 0; ct < 4; ++ct)
#pragma unroll
    for (int mt = 0; mt < 2; ++mt)
#pragma unroll
      for (int r = 0; r < 4; ++r) {
        int m = m0 + mt * 16 + lg * 4 + r;
        if (m < N) {
          C0[(size_t)m * 64 + ct * 16 + lr] = f2bf(acc0[mt][ct][r]);
          C1[(size_t)m * 64 + ct * 16 + lr] = f2bf(acc1[mt][ct][r]);
        }
      }
}

// ---------- segment-max: 16 entries in flight per loop step ----------
__global__ __launch_bounds__(256) void k_aggmax(
    const unsigned short* __restrict__ Htb, const int* __restrict__ offsets,
    const int* __restrict__ entries, unsigned short* __restrict__ mh, int N) {
  int w = threadIdx.x >> 6, lane = threadIdx.x & 63;
  int n = blockIdx.x * 4 + w;
  if (n >= N) return;
  int beg = offsets[n], end = offsets[n + 1];
  int g = lane >> 4, q = lane & 15;
  float a0 = -3.4e38f, a1 = a0, a2 = a0, a3 = a0;
  float b0 = a0, b1 = a0, b2 = a0, b3 = a0;
  float c0 = a0, c1 = a0, c2 = a0, c3 = a0;
  float d0 = a0, d1 = a0, d2 = a0, d3 = a0;
  int i = beg;
  for (; i + 16 <= end; i += 16) {
    int eA = entries[i + g];
    int eB = entries[i + 4 + g];
    int eC = entries[i + 8 + g];
    int eD = entries[i + 12 + g];
    ushort4 va = *(const ushort4*)&Htb[(size_t)eA * 64 + q * 4];
    ushort4 vb = *(const ushort4*)&Htb[(size_t)eB * 64 + q * 4];
    ushort4 vc = *(const ushort4*)&Htb[(size_t)eC * 64 + q * 4];
    ushort4 vd = *(const ushort4*)&Htb[(size_t)eD * 64 + q * 4];
    a0 = fmaxf(a0, bf2f(va.x)); a1 = fmaxf(a1, bf2f(va.y));
    a2 = fmaxf(a2, bf2f(va.z)); a3 = fmaxf(a3, bf2f(va.w));
    b0 = fmaxf(b0, bf2f(vb.x)); b1 = fmaxf(b1, bf2f(vb.y));
    b2 = fmaxf(b2, bf2f(vb.z)); b3 = fmaxf(b3, bf2f(vb.w));
    c0 = fmaxf(c0, bf2f(vc.x)); c1 = fmaxf(c1, bf2f(vc.y));
    c2 = fmaxf(c2, bf2f(vc.z)); c3 = fmaxf(c3, bf2f(vc.w));
    d0 = fmaxf(d0, bf2f(vd.x)); d1 = fmaxf(d1, bf2f(vd.y));
    d2 = fmaxf(d2, bf2f(vd.z)); d3 = fmaxf(d3, bf2f(vd.w));
  }
  for (; i + 8 <= end; i += 8) {
    int eA = entries[i + g];
    int eB = entries[i + 4 + g];
    ushort4 va = *(const ushort4*)&Htb[(size_t)eA * 64 + q * 4];
    ushort4 vb = *(const ushort4*)&Htb[(size_t)eB * 64 + q * 4];
    a0 = fmaxf(a0, bf2f(va.x)); a1 = fmaxf(a1, bf2f(va.y));
    a2 = fmaxf(a2, bf2f(va.z)); a3 = fmaxf(a3, bf2f(va.w));
    b0 = fmaxf(b0, bf2f(vb.x)); b1 = fmaxf(b1, bf2f(vb.y));
    b2 = fmaxf(b2, bf2f(vb.z)); b3 = fmaxf(b3, bf2f(vb.w));
  }
  for (; i < end; i += 4) {
    int idx = min(i + g, end - 1);  // clamped dup loads harmless for max
    int e = entries[idx];
    ushort4 va = *(const ushort4*)&Htb[(size_t)e * 64 + q * 4];
    a0 = fmaxf(a0, bf2f(va.x)); a1 = fmaxf(a1, bf2f(va.y));
    a2 = fmaxf(a2, bf2f(va.z)); a3 = fmaxf(a3, bf2f(va.w));
  }
  a0 = fmaxf(fmaxf(a0, b0), fmaxf(c0, d0));
  a1 = fmaxf(fmaxf(a1, b1), fmaxf(c1, d1));
  a2 = fmaxf(fmaxf(a2, b2), fmaxf(c2, d2));
  a3 = fmaxf(fmaxf(a3, b3), fmaxf(c3, d3));
  a0 = fmaxf(a0, __shfl_xor(a0, 16)); a1 = fmaxf(a1, __shfl_xor(a1, 16));
  a2 = fmaxf(a2, __shfl_xor(a2, 16)); a3 = fmaxf(a3, __shfl_xor(a3, 16));
  a0 = fmaxf(a0, __shfl_xor(a0, 32)); a1 = fmaxf(a1, __shfl_xor(a1, 32));
  a2 = fmaxf(a2, __shfl_xor(a2, 32)); a3 = fmaxf(a3, __shfl_xor(a3, 32));
  if (g == 0) {
    ushort4 o;
    if (end > beg) {
      o.x = f2bf(a0); o.y = f2bf(a1); o.z = f2bf(a2); o.w = f2bf(a3);
    } else {
      o.x = 0; o.y = 0; o.z = 0; o.w = 0;
    }
    *(ushort4*)&mh[(size_t)n * 64 + q * 4] = o;
  }
}

// ---------- fused GRU + next-step transform (same grid, same tile) ----------
// FINAL=0: gru0 (x=msg global), write h, stage new h (single bf16) in LDS,
//          transform -> HtW. FINAL=1: gru1, write f32 out; no transform.
// All LDS rows are wave-local -> NO __syncthreads.
template <int FINAL>
__global__ __launch_bounds__(256) void k_gt(
    const unsigned short* __restrict__ x0, const unsigned short* __restrict__ x1,
    unsigned short* __restrict__ hh, unsigned short* __restrict__ hl,
    const unsigned short* __restrict__ Wxf, const unsigned short* __restrict__ Whf,
    const float* __restrict__ bias, const unsigned short* __restrict__ eWf,
    unsigned short* __restrict__ HtW, float* __restrict__ outF, int N) {
  __shared__ __align__(16) char lds_hs[FINAL ? 16 : 128 * 128]; // 16 KB (hi only)
  int tid = threadIdx.x;
  int wv = tid >> 6, lane = tid & 63;
  int lr = lane & 15, lg = lane >> 4;
  int lbase = wv * 32;
  int m0 = blockIdx.x * 128 + lbase;

  const int NKCX = FINAL ? 4 : 2;
  v4f acc[2][12] = {};   // xr,xu,xc (+hr,hu merged)
  v4f acch[2][4] = {};   // hc separate
#pragma unroll
  for (int kc = 0; kc < NKCX; ++kc) {
    const unsigned short* X = (FINAL && kc >= 2) ? x1 : x0;
    int kcl = kc & 1;
    v8s ax[2];
#pragma unroll
    for (int mt = 0; mt < 2; ++mt) {
      int row = min(m0 + mt * 16 + lr, N - 1);
      ax[mt] = *(const v8s*)&X[(size_t)row * 64 + kcl * 32 + lg * 8];
    }
#pragma unroll
    for (int ct = 0; ct < 12; ++ct) {
      v8s bh = *(const v8s*)&Wxf[((size_t)(kc * 12 + ct)) * 512 + lane * 8];
      v8s bl = *(const v8s*)&Wxf[((size_t)((NKCX + kc) * 12 + ct)) * 512 + lane * 8];
#pragma unroll
      for (int mt = 0; mt < 2; ++mt) {
        acc[mt][ct] = __builtin_amdgcn_mfma_f32_16x16x32_bf16(ax[mt], bh, acc[mt][ct], 0, 0, 0);
        acc[mt][ct] = __builtin_amdgcn_mfma_f32_16x16x32_bf16(ax[mt], bl, acc[mt][ct], 0, 0, 0);
      }
    }
  }
#pragma unroll
  for (int kc = 0; kc < 2; ++kc) {
    v8s ah[2], al[2];
#pragma unroll
    for (int mt = 0; mt < 2; ++mt) {
      int row = min(m0 + mt * 16 + lr, N - 1);
      size_t off = (size_t)row * 64 + kc * 32 + lg * 8;
      ah[mt] = *(const v8s*)&hh[off];
      al[mt] = *(const v8s*)&hl[off];
    }
#pragma unroll
    for (int ct = 0; ct < 12; ++ct) {
      v8s bh = *(const v8s*)&Whf[((size_t)(kc * 12 + ct)) * 512 + lane * 8];
      v8s bl = *(const v8s*)&Whf[((size_t)((2 + kc) * 12 + ct)) * 512 + lane * 8];
#pragma unroll
      for (int mt = 0; mt < 2; ++mt) {
        v4f* d = (ct < 8) ? &acc[mt][ct] : &acch[mt][ct - 8];
        *d = __builtin_amdgcn_mfma_f32_16x16x32_bf16(ah[mt], bh, *d, 0, 0, 0);
        *d = __builtin_amdgcn_mfma_f32_16x16x32_bf16(al[mt], bh, *d, 0, 0, 0);
        *d = __builtin_amdgcn_mfma_f32_16x16x32_bf16(ah[mt], bl, *d, 0, 0, 0);
      }
    }
  }
  // gate epilogue
#pragma unroll
  for (int mt = 0; mt < 2; ++mt)
#pragma unroll
    for (int ctg = 0; ctg < 4; ++ctg)
#pragma unroll
      for (int r = 0; r < 4; ++r) {
        int m = m0 + mt * 16 + lg * 4 + r;
        int col = ctg * 16 + lr;
        unsigned short hbv = hh[(size_t)min(m, N - 1) * 64 + col];
        unsigned short hlv = hl[(size_t)min(m, N - 1) * 64 + col];
        float hv = bf2f(hbv) + bf2f(hlv);
        float rr = sigmoidf_(acc[mt][ctg][r] + bias[col]);
        float uu = sigmoidf_(acc[mt][ctg + 4][r] + bias[64 + col]);
        float cc = tanhf_(acc[mt][ctg + 8][r] + bias[128 + col] + rr * acch[mt][ctg][r]);
        float ho = uu * hv + (1.f - uu) * cc;
        if (FINAL) {
          if (m < N) outF[(size_t)m * 64 + col] = ho;
        } else {
          unsigned short ohi = f2bf(ho);
          unsigned short olo = f2bf(ho - bf2f(ohi));
          if (m < N) {
            hh[(size_t)m * 64 + col] = ohi;
            hl[(size_t)m * 64 + col] = olo;
          }
          int row = lbase + mt * 16 + lg * 4 + r;
          *(unsigned short*)(lds_hs + swz(row, col * 2)) = ohi;
        }
      }

  if (FINAL) return;

  // ---- transform new h (single bf16) -> HtW for all 8 types (2 per pass) ----
  v8s tah[2][2];  // [kc][mt]
#pragma unroll
  for (int kc = 0; kc < 2; ++kc)
#pragma unroll
    for (int mt = 0; mt < 2; ++mt) {
      int row = lbase + mt * 16 + lr;
      tah[kc][mt] = *(const v8s*)(lds_hs + swz(row, kc * 64 + lg * 16));
    }
#pragma unroll
  for (int y = 0; y < 4; ++y) {
    const unsigned short* W0 = eWf + (size_t)y * 8192;
    const unsigned short* W1 = eWf + (size_t)(y + 4) * 8192;
    unsigned short* C0 = HtW + (size_t)y * N * 64;
    unsigned short* C1 = HtW + (size_t)(y + 4) * N * 64;
    v4f acc0[2][4] = {}, acc1[2][4] = {};
#pragma unroll
    for (int kc = 0; kc < 2; ++kc)
#pragma unroll
      for (int ct = 0; ct < 4; ++ct) {
        v8s bh0 = *(const v8s*)&W0[((size_t)(kc * 4 + ct)) * 512 + lane * 8];
        v8s bl0 = *(const v8s*)&W0[((size_t)((2 + kc) * 4 + ct)) * 512 + lane * 8];
        v8s bh1 = *(const v8s*)&W1[((size_t)(kc * 4 + ct)) * 512 + lane * 8];
        v8s bl1 = *(const v8s*)&W1[((size_t)((2 + kc) * 4 + ct)) * 512 + lane * 8];
#pragma unroll
        for (int mt = 0; mt < 2; ++mt) {
          acc0[mt][ct] = __builtin_amdgcn_mfma_f32_16x16x32_bf16(tah[kc][mt], bh0, acc0[mt][ct], 0, 0, 0);
          acc0[mt][ct] = __builtin_amdgcn_mfma_f32_16x16x32_bf16(tah[kc][mt], bl0, acc0[mt][ct], 0, 0, 0);
          acc1[mt][ct] = __builtin_amdgcn_mfma_f32_16x16x32_bf16(tah[kc][mt], bh1, acc1[mt][ct], 0, 0, 0);
          acc1[mt][ct] = __builtin_amdgcn_mfma_f32_16x16x32_bf16(tah[kc][mt], bl1, acc1[mt][ct], 0, 0, 0);
        }
      }
#pragma unroll
    for (int ct = 0; ct < 4; ++ct)
#pragma unroll
      for (int mt = 0; mt < 2; ++mt)
#pragma unroll
        for (int r = 0; r < 4; ++r) {
          int m = m0 + mt * 16 + lg * 4 + r;
          if (m < N) {
            C0[(size_t)m * 64 + ct * 16 + lr] = f2bf(acc0[mt][ct][r]);
            C1[(size_t)m * 64 + ct * 16 + lr] = f2bf(acc1[mt][ct][r]);
          }
        }
  }
}

extern "C" void kernel_launch(void* const* d_in, const int* in_sizes, int n_in,
                              void* d_out, int out_size, void* d_ws, size_t ws_size,
                              hipStream_t stream) {
  const int*   toks  = (const int*)d_in[0];
  const int*   adj   = (const int*)d_in[1];
  const float* embed = (const float*)d_in[2];
  const float* projW = (const float*)d_in[3];
  const float* eW0   = (const float*)d_in[4];
  const float* eW1   = (const float*)d_in[5];
  const float* g0Wx  = (const float*)d_in[6];
  const float* g0Wh  = (const float*)d_in[7];
  const float* g0b   = (const float*)d_in[8];
  const float* g1Wx  = (const float*)d_in[9];
  const float* g1Wh  = (const float*)d_in[10];
  const float* g1b   = (const float*)d_in[11];
  float* out = (float*)d_out;

  int N = in_sizes[0] / 5;
  int E = in_sizes[1] / 8;
  size_t ND = (size_t)N * 64;

  char* p = (char*)d_ws;
  unsigned short* Htb     = (unsigned short*)p; p += 8 * ND * 2;   // 61.4 MB
  unsigned short* h_hi    = (unsigned short*)p; p += ND * 2;
  unsigned short* h_lo    = (unsigned short*)p; p += ND * 2;
  unsigned short* hinit_b = (unsigned short*)p; p += ND * 2;
  unsigned short* m_hi    = (unsigned short*)p; p += ND * 2;
  int* offsets = (int*)p; p += (size_t)(N + 64) * sizeof(int);
  int* cnt_cur = (int*)p; p += (size_t)(N + 64) * sizeof(int);
  int* entries = (int*)p; p += (size_t)8 * E * sizeof(int);
  unsigned short* eW0f  = (unsigned short*)p; p += 65536 * 2;
  unsigned short* eW1f  = (unsigned short*)p; p += 65536 * 2;
  unsigned short* projf = (unsigned short*)p; p += 8192 * 2;
  unsigned short* g0xf  = (unsigned short*)p; p += 24576 * 2;
  unsigned short* g0hf  = (unsigned short*)p; p += 24576 * 2;
  unsigned short* g1xf  = (unsigned short*)p; p += 49152 * 2;
  unsigned short* g1hf  = (unsigned short*)p; p += 24576 * 2;
  if ((size_t)(p - (char*)d_ws) > ws_size) return;

  // init-phase aliases inside Htb (consumed by k_proj before k_mm_t writes Htb)
  unsigned short* emb_h = Htb;
  unsigned short* emb_l = Htb + ND;

  int g128 = (N + 127) / 128;
  int g4 = (N + 3) / 4;

  k_wprep_all<<<1024, 256, 0, stream>>>(eW0, eW1, projW, g0Wx, g0Wh, g1Wx, g1Wh,
                                        eW0f, eW1f, projf, g0xf, g0hf, g1xf, g1hf);
  hipMemsetAsync(cnt_cur, 0, (size_t)N * sizeof(int), stream);
  dim3 egrid((E + 255) / 256, 4);
  k_counts<<<egrid, 256, 0, stream>>>(adj, cnt_cur, E);
  k_embed<<<g4, 256, 0, stream>>>(toks, embed, emb_h, emb_l, N);
  k_proj<<<g128, 256, 0, stream>>>(emb_h, emb_l, projf, h_hi, h_lo, hinit_b, N);
  k_scan<<<1, 1024, 0, stream>>>(cnt_cur, offsets, cnt_cur, N);
  k_fill<<<egrid, 256, 0, stream>>>(adj, cnt_cur, entries, E, N);
  // initial transform (step-0 messages): h_init -> Htb with eW0
  k_mm_t<<<dim3(g128, 4), 256, 0, stream>>>(h_hi, h_lo, eW0f, Htb, N);

  for (int it = 0; it < 7; ++it) {
    k_aggmax<<<g4, 256, 0, stream>>>(Htb, offsets, entries, m_hi, N);
    // gru0 + transform of the NEW h for step it+1 (eW1 when it+1 == 7)
    const unsigned short* ef = (it < 6) ? eW0f : eW1f;
    k_gt<0><<<g128, 256, 0, stream>>>(m_hi, nullptr, h_hi, h_lo,
                                      g0xf, g0hf, g0b, ef, Htb, nullptr, N);
  }
  k_aggmax<<<g4, 256, 0, stream>>>(Htb, offsets, entries, m_hi, N);
  k_gt<1><<<g128, 256, 0, stream>>>(hinit_b, m_hi, h_hi, h_lo,
                                    g1xf, g1hf, g1b, nullptr, nullptr, out, N);
}

// Round 11
// 1088.917 us; speedup vs baseline: 1.1259x; 1.0003x over previous
//
#include <hip/hip_runtime.h>

typedef short v8s __attribute__((ext_vector_type(8)));
typedef float v4f __attribute__((ext_vector_type(4)));

__device__ __forceinline__ unsigned short f2bf(float x) {
  unsigned u = __float_as_uint(x);
  u = u + 0x7FFFu + ((u >> 16) & 1u);
  return (unsigned short)(u >> 16);
}
__device__ __forceinline__ float bf2f(unsigned short b) {
  return __uint_as_float(((unsigned)b) << 16);
}
__device__ __forceinline__ float sigmoidf_(float x) {
  return 1.f / (1.f + __expf(-x));
}
__device__ __forceinline__ float tanhf_(float x) {
  x = fminf(fmaxf(x, -20.f), 20.f);
  float e2 = __expf(2.f * x);
  return (e2 - 1.f) / (e2 + 1.f);
}
// LDS swizzle: XOR byte-bits 4-6 with row&7 (rows are 128 B) -> 2-way max.
__device__ __forceinline__ int swz(int row, int byteInRow) {
  return row * 128 + (byteInRow ^ ((row & 7) << 4));
}

// ---------- weight prep (device) ----------
// frag layout per weight: idx = ((p*nkc + kc)*nct + ct)*512 + lane*8 + j
// value: W[t][kc*32+(lane>>4)*8+j][ct*16+(lane&15)], p=0 hi, p=1 lo.
__device__ __forceinline__ void wprep_one(const float* W, unsigned short* O,
                                          int K, int J, int idx) {
  int nkc = K >> 5, nct = J >> 4;
  int j = idx & 7, lane = (idx >> 3) & 63;
  int rest = idx >> 9;
  int ct = rest % nct; rest /= nct;
  int kc = rest % nkc; rest /= nkc;
  int p = rest & 1, t = rest >> 1;
  int row = kc * 32 + (lane >> 4) * 8 + j;
  int col = ct * 16 + (lane & 15);
  float v = W[(size_t)t * K * J + (size_t)row * J + col];
  unsigned short hi = f2bf(v);
  O[idx] = p ? f2bf(v - bf2f(hi)) : hi;
}

// ---------- setup1: counts || embed || wprep (block-partitioned) ----------
__global__ __launch_bounds__(256) void k_setup1(
    const int* __restrict__ adj, int* __restrict__ counts, int E, int ex,
    const int* __restrict__ toks, const float* __restrict__ embed,
    unsigned short* __restrict__ eh, unsigned short* __restrict__ el, int N, int g4,
    const float* eW0, const float* eW1, const float* projW,
    const float* g0Wx, const float* g0Wh, const float* g1Wx, const float* g1Wh,
    unsigned short* eW0f, unsigned short* eW1f, unsigned short* projf,
    unsigned short* g0xf, unsigned short* g0hf,
    unsigned short* g1xf, unsigned short* g1hf) {
  int b = blockIdx.x;
  int tid = threadIdx.x;
  if (b < 4 * ex) {
    // ---- counts: thread handles fwd+bwd of one edge ----
    int t4 = b / ex, eb = b % ex;
    int e = eb * 256 + tid;
    if (e >= E) return;
    int2 ab = *(const int2*)&adj[(size_t)(t4 * E + e) * 2];
    atomicAdd(&counts[ab.y], 1);
    atomicAdd(&counts[ab.x], 1);
    return;
  }
  b -= 4 * ex;
  if (b < g4) {
    // ---- embed: coalesced, 64 lanes = 64 features ----
    int w = tid >> 6, lane = tid & 63;
    int n = b * 4 + w;
    if (n >= N) return;
    float acc = 0.f;
#pragma unroll
    for (int s = 0; s < 5; ++s)
      acc += embed[(size_t)toks[n * 5 + s] * 64 + lane];
    float v = acc * 0.2f;
    unsigned short h = f2bf(v);
    eh[(size_t)n * 64 + lane] = h;
    el[(size_t)n * 64 + lane] = f2bf(v - bf2f(h));
    return;
  }
  b -= g4;
  // ---- wprep ----
  int rel = b * 256 + tid;
  if (rel < 65536) { wprep_one(eW0, eW0f, 64, 64, rel); return; }
  rel -= 65536;
  if (rel < 65536) { wprep_one(eW1, eW1f, 64, 64, rel); return; }
  rel -= 65536;
  if (rel < 8192)  { wprep_one(projW, projf, 64, 64, rel); return; }
  rel -= 8192;
  if (rel < 24576) { wprep_one(g0Wx, g0xf, 64, 192, rel); return; }
  rel -= 24576;
  if (rel < 24576) { wprep_one(g0Wh, g0hf, 64, 192, rel); return; }
  rel -= 24576;
  if (rel < 49152) { wprep_one(g1Wx, g1xf, 128, 192, rel); return; }
  rel -= 49152;
  if (rel < 24576) { wprep_one(g1Wh, g1hf, 64, 192, rel); return; }
}

// ---------- scan: counts -> offsets[0..n] and cursor copy ----------
__global__ __launch_bounds__(1024) void k_scan(const int* __restrict__ counts,
                                               int* __restrict__ offsets,
                                               int* __restrict__ cursor, int n) {
  __shared__ int part[1024];
  int tid = threadIdx.x;
  int chunk = (((n + 1023) >> 10) + 3) & ~3;
  int begin = tid * chunk;
  int end = min(begin + chunk, n);
  int s = 0;
  int i = begin;
  for (; i + 4 <= end; i += 4) {
    int4 v = *(const int4*)&counts[i];
    s += v.x + v.y + v.z + v.w;
  }
  for (; i < end; ++i) s += counts[i];
  part[tid] = s;
  __syncthreads();
  for (int off = 1; off < 1024; off <<= 1) {
    int v = (tid >= off) ? part[tid - off] : 0;
    __syncthreads();
    part[tid] += v;
    __syncthreads();
  }
  int run = part[tid] - s;
  i = begin;
  for (; i + 4 <= end; i += 4) {
    int4 c = *(const int4*)&counts[i];
    int4 o;
    o.x = run; o.y = run + c.x; o.z = o.y + c.y; o.w = o.z + c.z;
    *(int4*)&offsets[i] = o;
    *(int4*)&cursor[i] = o;
    run = o.w + c.w;
  }
  for (; i < end; ++i) {
    offsets[i] = run; cursor[i] = run; run += counts[i];
  }
  if (tid == 1023) offsets[n] = part[1023];
}

// ---------- setup2: fill || proj (block-partitioned) ----------
__global__ __launch_bounds__(256) void k_setup2(
    const int* __restrict__ adj, int* __restrict__ cursor,
    int* __restrict__ entries, int E, int ex, int N,
    const unsigned short* __restrict__ A0h, const unsigned short* __restrict__ A0l,
    const unsigned short* __restrict__ Wf,
    unsigned short* __restrict__ h_hi, unsigned short* __restrict__ h_lo,
    unsigned short* __restrict__ hinit_b) {
  int b = blockIdx.x;
  int tid = threadIdx.x;
  if (b < 4 * ex) {
    // ---- fill ----
    int t4 = b / ex, eb = b % ex;
    int e = eb * 256 + tid;
    if (e >= E) return;
    int2 ab = *(const int2*)&adj[(size_t)(t4 * E + e) * 2];
    int p1 = atomicAdd(&cursor[ab.y], 1);
    entries[p1] = t4 * N + ab.x;
    int p2 = atomicAdd(&cursor[ab.x], 1);
    entries[p2] = (t4 + 4) * N + ab.y;
    return;
  }
  b -= 4 * ex;
  // ---- proj: h_init = emb @ projW ----
  int wv = tid >> 6, lane = tid & 63;
  int lr = lane & 15, lg = lane >> 4;
  int m0 = b * 128 + wv * 32;
  v4f acc[2][4] = {};
#pragma unroll
  for (int kc = 0; kc < 2; ++kc) {
    v8s ah[2], al[2];
#pragma unroll
    for (int mt = 0; mt < 2; ++mt) {
      int row = min(m0 + mt * 16 + lr, N - 1);
      size_t off = (size_t)row * 64 + kc * 32 + lg * 8;
      ah[mt] = *(const v8s*)&A0h[off];
      al[mt] = *(const v8s*)&A0l[off];
    }
#pragma unroll
    for (int ct = 0; ct < 4; ++ct) {
      v8s bh = *(const v8s*)&Wf[((size_t)(kc * 4 + ct)) * 512 + lane * 8];
      v8s bl = *(const v8s*)&Wf[((size_t)((2 + kc) * 4 + ct)) * 512 + lane * 8];
#pragma unroll
      for (int mt = 0; mt < 2; ++mt) {
        acc[mt][ct] = __builtin_amdgcn_mfma_f32_16x16x32_bf16(ah[mt], bh, acc[mt][ct], 0, 0, 0);
        acc[mt][ct] = __builtin_amdgcn_mfma_f32_16x16x32_bf16(al[mt], bh, acc[mt][ct], 0, 0, 0);
        acc[mt][ct] = __builtin_amdgcn_mfma_f32_16x16x32_bf16(ah[mt], bl, acc[mt][ct], 0, 0, 0);
      }
    }
  }
#pragma unroll
  for (int ct = 0; ct < 4; ++ct)
#pragma unroll
    for (int mt = 0; mt < 2; ++mt)
#pragma unroll
      for (int r = 0; r < 4; ++r) {
        int m = m0 + mt * 16 + lg * 4 + r;
        if (m >= N) continue;
        int col = ct * 16 + lr;
        float v = acc[mt][ct][r];
        unsigned short hb = f2bf(v);
        h_hi[(size_t)m * 64 + col] = hb;
        h_lo[(size_t)m * 64 + col] = f2bf(v - bf2f(hb));
        hinit_b[(size_t)m * 64 + col] = hb;
      }
}

// ---------- initial transform: Ht[t][n] = h[n] @ W[t], 2 types per block ----------
__global__ __launch_bounds__(256) void k_mm_t(
    const unsigned short* __restrict__ A0h, const unsigned short* __restrict__ A0l,
    const unsigned short* __restrict__ Wf, unsigned short* __restrict__ C16,
    int N) {
  int tid = threadIdx.x;
  int wv = tid >> 6, lane = tid & 63;
  int lr = lane & 15, lg = lane >> 4;
  int y = blockIdx.y;
  const unsigned short* W0 = Wf + (size_t)y * 8192;
  const unsigned short* W1 = Wf + (size_t)(y + 4) * 8192;
  unsigned short* C0 = C16 + (size_t)y * N * 64;
  unsigned short* C1 = C16 + (size_t)(y + 4) * N * 64;
  int m0 = blockIdx.x * 128 + wv * 32;
  v4f acc0[2][4] = {}, acc1[2][4] = {};
#pragma unroll
  for (int kc = 0; kc < 2; ++kc) {
    v8s ah[2], al[2];
#pragma unroll
    for (int mt = 0; mt < 2; ++mt) {
      int row = min(m0 + mt * 16 + lr, N - 1);
      size_t off = (size_t)row * 64 + kc * 32 + lg * 8;
      ah[mt] = *(const v8s*)&A0h[off];
      al[mt] = *(const v8s*)&A0l[off];
    }
#pragma unroll
    for (int ct = 0; ct < 4; ++ct) {
      v8s bh0 = *(const v8s*)&W0[((size_t)(kc * 4 + ct)) * 512 + lane * 8];
      v8s bl0 = *(const v8s*)&W0[((size_t)((2 + kc) * 4 + ct)) * 512 + lane * 8];
      v8s bh1 = *(const v8s*)&W1[((size_t)(kc * 4 + ct)) * 512 + lane * 8];
      v8s bl1 = *(const v8s*)&W1[((size_t)((2 + kc) * 4 + ct)) * 512 + lane * 8];
#pragma unroll
      for (int mt = 0; mt < 2; ++mt) {
        acc0[mt][ct] = __builtin_amdgcn_mfma_f32_16x16x32_bf16(ah[mt], bh0, acc0[mt][ct], 0, 0, 0);
        acc0[mt][ct] = __builtin_amdgcn_mfma_f32_16x16x32_bf16(al[mt], bh0, acc0[mt][ct], 0, 0, 0);
        acc0[mt][ct] = __builtin_amdgcn_mfma_f32_16x16x32_bf16(ah[mt], bl0, acc0[mt][ct], 0, 0, 0);
        acc1[mt][ct] = __builtin_amdgcn_mfma_f32_16x16x32_bf16(ah[mt], bh1, acc1[mt][ct], 0, 0, 0);
        acc1[mt][ct] = __builtin_amdgcn_mfma_f32_16x16x32_bf16(al[mt], bh1, acc1[mt][ct], 0, 0, 0);
        acc1[mt][ct] = __builtin_amdgcn_mfma_f32_16x16x32_bf16(ah[mt], bl1, acc1[mt][ct], 0, 0, 0);
      }
    }
  }
#pragma unroll
  for (int ct = 0; ct < 4; ++ct)
#pragma unroll
    for (int mt = 0; mt < 2; ++mt)
#pragma unroll
      for (int r = 0; r < 4; ++r) {
        int m = m0 + mt * 16 + lg * 4 + r;
        if (m < N) {
          C0[(size_t)m * 64 + ct * 16 + lr] = f2bf(acc0[mt][ct][r]);
          C1[(size_t)m * 64 + ct * 16 + lr] = f2bf(acc1[mt][ct][r]);
        }
      }
}

// ---------- segment-max: coalesced entry loads + shfl broadcast ----------
// Per 16-entry round: 1 entry load (lane&15) + 4 shuffles + 4 row gathers.
__global__ __launch_bounds__(256) void k_aggmax(
    const unsigned short* __restrict__ Htb, const int* __restrict__ offsets,
    const int* __restrict__ entries, unsigned short* __restrict__ mh, int N) {
  int w = threadIdx.x >> 6, lane = threadIdx.x & 63;
  int n = blockIdx.x * 4 + w;
  if (n >= N) return;
  int beg = offsets[n], end = offsets[n + 1];
  int g = lane >> 4, q = lane & 15;
  float a0 = -3.4e38f, a1 = a0, a2 = a0, a3 = a0;
  float b0 = a0, b1 = a0, b2 = a0, b3 = a0;
  float c0 = a0, c1 = a0, c2 = a0, c3 = a0;
  float d0 = a0, d1 = a0, d2 = a0, d3 = a0;
  for (int i = beg; i < end; i += 16) {
    int li = min(i + (lane & 15), end - 1);  // clamped dups harmless for max
    int ei = entries[li];
    int eA = __shfl(ei, g);
    int eB = __shfl(ei, g + 4);
    int eC = __shfl(ei, g + 8);
    int eD = __shfl(ei, g + 12);
    ushort4 va = *(const ushort4*)&Htb[(size_t)eA * 64 + q * 4];
    ushort4 vb = *(const ushort4*)&Htb[(size_t)eB * 64 + q * 4];
    ushort4 vc = *(const ushort4*)&Htb[(size_t)eC * 64 + q * 4];
    ushort4 vd = *(const ushort4*)&Htb[(size_t)eD * 64 + q * 4];
    a0 = fmaxf(a0, bf2f(va.x)); a1 = fmaxf(a1, bf2f(va.y));
    a2 = fmaxf(a2, bf2f(va.z)); a3 = fmaxf(a3, bf2f(va.w));
    b0 = fmaxf(b0, bf2f(vb.x)); b1 = fmaxf(b1, bf2f(vb.y));
    b2 = fmaxf(b2, bf2f(vb.z)); b3 = fmaxf(b3, bf2f(vb.w));
    c0 = fmaxf(c0, bf2f(vc.x)); c1 = fmaxf(c1, bf2f(vc.y));
    c2 = fmaxf(c2, bf2f(vc.z)); c3 = fmaxf(c3, bf2f(vc.w));
    d0 = fmaxf(d0, bf2f(vd.x)); d1 = fmaxf(d1, bf2f(vd.y));
    d2 = fmaxf(d2, bf2f(vd.z)); d3 = fmaxf(d3, bf2f(vd.w));
  }
  a0 = fmaxf(fmaxf(a0, b0), fmaxf(c0, d0));
  a1 = fmaxf(fmaxf(a1, b1), fmaxf(c1, d1));
  a2 = fmaxf(fmaxf(a2, b2), fmaxf(c2, d2));
  a3 = fmaxf(fmaxf(a3, b3), fmaxf(c3, d3));
  a0 = fmaxf(a0, __shfl_xor(a0, 16)); a1 = fmaxf(a1, __shfl_xor(a1, 16));
  a2 = fmaxf(a2, __shfl_xor(a2, 16)); a3 = fmaxf(a3, __shfl_xor(a3, 16));
  a0 = fmaxf(a0, __shfl_xor(a0, 32)); a1 = fmaxf(a1, __shfl_xor(a1, 32));
  a2 = fmaxf(a2, __shfl_xor(a2, 32)); a3 = fmaxf(a3, __shfl_xor(a3, 32));
  if (g == 0) {
    ushort4 o;
    if (end > beg) {
      o.x = f2bf(a0); o.y = f2bf(a1); o.z = f2bf(a2); o.w = f2bf(a3);
    } else {
      o.x = 0; o.y = 0; o.z = 0; o.w = 0;
    }
    *(ushort4*)&mh[(size_t)n * 64 + q * 4] = o;
  }
}

// ---------- fused GRU + next-step transform (same grid, same tile) ----------
// FINAL=0: gru0 (x=msg global), write h, stage new h (single bf16) in LDS,
//          transform -> HtW. FINAL=1: gru1, write f32 out; no transform.
// All LDS rows are wave-local -> NO __syncthreads.
template <int FINAL>
__global__ __launch_bounds__(256) void k_gt(
    const unsigned short* __restrict__ x0, const unsigned short* __restrict__ x1,
    unsigned short* __restrict__ hh, unsigned short* __restrict__ hl,
    const unsigned short* __restrict__ Wxf, const unsigned short* __restrict__ Whf,
    const float* __restrict__ bias, const unsigned short* __restrict__ eWf,
    unsigned short* __restrict__ HtW, float* __restrict__ outF, int N) {
  __shared__ __align__(16) char lds_hs[FINAL ? 16 : 128 * 128]; // 16 KB (hi only)
  int tid = threadIdx.x;
  int wv = tid >> 6, lane = tid & 63;
  int lr = lane & 15, lg = lane >> 4;
  int lbase = wv * 32;
  int m0 = blockIdx.x * 128 + lbase;

  const int NKCX = FINAL ? 4 : 2;
  v4f acc[2][12] = {};   // xr,xu,xc (+hr,hu merged)
  v4f acch[2][4] = {};   // hc separate
#pragma unroll
  for (int kc = 0; kc < NKCX; ++kc) {
    const unsigned short* X = (FINAL && kc >= 2) ? x1 : x0;
    int kcl = kc & 1;
    v8s ax[2];
#pragma unroll
    for (int mt = 0; mt < 2; ++mt) {
      int row = min(m0 + mt * 16 + lr, N - 1);
      ax[mt] = *(const v8s*)&X[(size_t)row * 64 + kcl * 32 + lg * 8];
    }
#pragma unroll
    for (int ct = 0; ct < 12; ++ct) {
      v8s bh = *(const v8s*)&Wxf[((size_t)(kc * 12 + ct)) * 512 + lane * 8];
      v8s bl = *(const v8s*)&Wxf[((size_t)((NKCX + kc) * 12 + ct)) * 512 + lane * 8];
#pragma unroll
      for (int mt = 0; mt < 2; ++mt) {
        acc[mt][ct] = __builtin_amdgcn_mfma_f32_16x16x32_bf16(ax[mt], bh, acc[mt][ct], 0, 0, 0);
        acc[mt][ct] = __builtin_amdgcn_mfma_f32_16x16x32_bf16(ax[mt], bl, acc[mt][ct], 0, 0, 0);
      }
    }
  }
#pragma unroll
  for (int kc = 0; kc < 2; ++kc) {
    v8s ah[2], al[2];
#pragma unroll
    for (int mt = 0; mt < 2; ++mt) {
      int row = min(m0 + mt * 16 + lr, N - 1);
      size_t off = (size_t)row * 64 + kc * 32 + lg * 8;
      ah[mt] = *(const v8s*)&hh[off];
      al[mt] = *(const v8s*)&hl[off];
    }
#pragma unroll
    for (int ct = 0; ct < 12; ++ct) {
      v8s bh = *(const v8s*)&Whf[((size_t)(kc * 12 + ct)) * 512 + lane * 8];
      v8s bl = *(const v8s*)&Whf[((size_t)((2 + kc) * 12 + ct)) * 512 + lane * 8];
#pragma unroll
      for (int mt = 0; mt < 2; ++mt) {
        v4f* d = (ct < 8) ? &acc[mt][ct] : &acch[mt][ct - 8];
        *d = __builtin_amdgcn_mfma_f32_16x16x32_bf16(ah[mt], bh, *d, 0, 0, 0);
        *d = __builtin_amdgcn_mfma_f32_16x16x32_bf16(al[mt], bh, *d, 0, 0, 0);
        *d = __builtin_amdgcn_mfma_f32_16x16x32_bf16(ah[mt], bl, *d, 0, 0, 0);
      }
    }
  }
  // gate epilogue
#pragma unroll
  for (int mt = 0; mt < 2; ++mt)
#pragma unroll
    for (int ctg = 0; ctg < 4; ++ctg)
#pragma unroll
      for (int r = 0; r < 4; ++r) {
        int m = m0 + mt * 16 + lg * 4 + r;
        int col = ctg * 16 + lr;
        unsigned short hbv = hh[(size_t)min(m, N - 1) * 64 + col];
        unsigned short hlv = hl[(size_t)min(m, N - 1) * 64 + col];
        float hv = bf2f(hbv) + bf2f(hlv);
        float rr = sigmoidf_(acc[mt][ctg][r] + bias[col]);
        float uu = sigmoidf_(acc[mt][ctg + 4][r] + bias[64 + col]);
        float cc = tanhf_(acc[mt][ctg + 8][r] + bias[128 + col] + rr * acch[mt][ctg][r]);
        float ho = uu * hv + (1.f - uu) * cc;
        if (FINAL) {
          if (m < N) outF[(size_t)m * 64 + col] = ho;
        } else {
          unsigned short ohi = f2bf(ho);
          unsigned short olo = f2bf(ho - bf2f(ohi));
          if (m < N) {
            hh[(size_t)m * 64 + col] = ohi;
            hl[(size_t)m * 64 + col] = olo;
          }
          int row = lbase + mt * 16 + lg * 4 + r;
          *(unsigned short*)(lds_hs + swz(row, col * 2)) = ohi;
        }
      }

  if (FINAL) return;

  // ---- transform new h (single bf16) -> HtW for all 8 types (2 per pass) ----
  v8s tah[2][2];  // [kc][mt]
#pragma unroll
  for (int kc = 0; kc < 2; ++kc)
#pragma unroll
    for (int mt = 0; mt < 2; ++mt) {
      int row = lbase + mt * 16 + lr;
      tah[kc][mt] = *(const v8s*)(lds_hs + swz(row, kc * 64 + lg * 16));
    }
#pragma unroll
  for (int y = 0; y < 4; ++y) {
    const unsigned short* W0 = eWf + (size_t)y * 8192;
    const unsigned short* W1 = eWf + (size_t)(y + 4) * 8192;
    unsigned short* C0 = HtW + (size_t)y * N * 64;
    unsigned short* C1 = HtW + (size_t)(y + 4) * N * 64;
    v4f acc0[2][4] = {}, acc1[2][4] = {};
#pragma unroll
    for (int kc = 0; kc < 2; ++kc)
#pragma unroll
      for (int ct = 0; ct < 4; ++ct) {
        v8s bh0 = *(const v8s*)&W0[((size_t)(kc * 4 + ct)) * 512 + lane * 8];
        v8s bl0 = *(const v8s*)&W0[((size_t)((2 + kc) * 4 + ct)) * 512 + lane * 8];
        v8s bh1 = *(const v8s*)&W1[((size_t)(kc * 4 + ct)) * 512 + lane * 8];
        v8s bl1 = *(const v8s*)&W1[((size_t)((2 + kc) * 4 + ct)) * 512 + lane * 8];
#pragma unroll
        for (int mt = 0; mt < 2; ++mt) {
          acc0[mt][ct] = __builtin_amdgcn_mfma_f32_16x16x32_bf16(tah[kc][mt], bh0, acc0[mt][ct], 0, 0, 0);
          acc0[mt][ct] = __builtin_amdgcn_mfma_f32_16x16x32_bf16(tah[kc][mt], bl0, acc0[mt][ct], 0, 0, 0);
          acc1[mt][ct] = __builtin_amdgcn_mfma_f32_16x16x32_bf16(tah[kc][mt], bh1, acc1[mt][ct], 0, 0, 0);
          acc1[mt][ct] = __builtin_amdgcn_mfma_f32_16x16x32_bf16(tah[kc][mt], bl1, acc1[mt][ct], 0, 0, 0);
        }
      }
#pragma unroll
    for (int ct = 0; ct < 4; ++ct)
#pragma unroll
      for (int mt = 0; mt < 2; ++mt)
#pragma unroll
        for (int r = 0; r < 4; ++r) {
          int m = m0 + mt * 16 + lg * 4 + r;
          if (m < N) {
            C0[(size_t)m * 64 + ct * 16 + lr] = f2bf(acc0[mt][ct][r]);
            C1[(size_t)m * 64 + ct * 16 + lr] = f2bf(acc1[mt][ct][r]);
          }
        }
  }
}

extern "C" void kernel_launch(void* const* d_in, const int* in_sizes, int n_in,
                              void* d_out, int out_size, void* d_ws, size_t ws_size,
                              hipStream_t stream) {
  const int*   toks  = (const int*)d_in[0];
  const int*   adj   = (const int*)d_in[1];
  const float* embed = (const float*)d_in[2];
  const float* projW = (const float*)d_in[3];
  const float* eW0   = (const float*)d_in[4];
  const float* eW1   = (const float*)d_in[5];
  const float* g0Wx  = (const float*)d_in[6];
  const float* g0Wh  = (const float*)d_in[7];
  const float* g0b   = (const float*)d_in[8];
  const float* g1Wx  = (const float*)d_in[9];
  const float* g1Wh  = (const float*)d_in[10];
  const float* g1b   = (const float*)d_in[11];
  float* out = (float*)d_out;

  int N = in_sizes[0] / 5;
  int E = in_sizes[1] / 8;
  size_t ND = (size_t)N * 64;

  char* p = (char*)d_ws;
  unsigned short* Htb     = (unsigned short*)p; p += 8 * ND * 2;   // 61.4 MB
  unsigned short* h_hi    = (unsigned short*)p; p += ND * 2;
  unsigned short* h_lo    = (unsigned short*)p; p += ND * 2;
  unsigned short* hinit_b = (unsigned short*)p; p += ND * 2;
  unsigned short* m_hi    = (unsigned short*)p; p += ND * 2;
  int* offsets = (int*)p; p += (size_t)(N + 64) * sizeof(int);
  int* cnt_cur = (int*)p; p += (size_t)(N + 64) * sizeof(int);
  int* entries = (int*)p; p += (size_t)8 * E * sizeof(int);
  unsigned short* eW0f  = (unsigned short*)p; p += 65536 * 2;
  unsigned short* eW1f  = (unsigned short*)p; p += 65536 * 2;
  unsigned short* projf = (unsigned short*)p; p += 8192 * 2;
  unsigned short* g0xf  = (unsigned short*)p; p += 24576 * 2;
  unsigned short* g0hf  = (unsigned short*)p; p += 24576 * 2;
  unsigned short* g1xf  = (unsigned short*)p; p += 49152 * 2;
  unsigned short* g1hf  = (unsigned short*)p; p += 24576 * 2;
  if ((size_t)(p - (char*)d_ws) > ws_size) return;

  // init-phase aliases inside Htb (consumed by proj before k_mm_t writes Htb)
  unsigned short* emb_h = Htb;
  unsigned short* emb_l = Htb + ND;

  int g128 = (N + 127) / 128;
  int g4 = (N + 3) / 4;
  int ex = (E + 255) / 256;

  hipMemsetAsync(cnt_cur, 0, (size_t)N * sizeof(int), stream);
  // setup1: counts [0,4ex) || embed [4ex,4ex+g4) || wprep (1024 blocks)
  k_setup1<<<4 * ex + g4 + 1024, 256, 0, stream>>>(
      adj, cnt_cur, E, ex, toks, embed, emb_h, emb_l, N, g4,
      eW0, eW1, projW, g0Wx, g0Wh, g1Wx, g1Wh,
      eW0f, eW1f, projf, g0xf, g0hf, g1xf, g1hf);
  k_scan<<<1, 1024, 0, stream>>>(cnt_cur, offsets, cnt_cur, N);
  // setup2: fill [0,4ex) || proj [4ex,4ex+g128)
  k_setup2<<<4 * ex + g128, 256, 0, stream>>>(
      adj, cnt_cur, entries, E, ex, N,
      emb_h, emb_l, projf, h_hi, h_lo, hinit_b);
  // initial transform (step-0 messages): h_init -> Htb with eW0
  k_mm_t<<<dim3(g128, 4), 256, 0, stream>>>(h_hi, h_lo, eW0f, Htb, N);

  for (int it = 0; it < 7; ++it) {
    k_aggmax<<<g4, 256, 0, stream>>>(Htb, offsets, entries, m_hi, N);
    // gru0 + transform of the NEW h for step it+1 (eW1 when it+1 == 7)
    const unsigned short* ef = (it < 6) ? eW0f : eW1f;
    k_gt<0><<<g128, 256, 0, stream>>>(m_hi, nullptr, h_hi, h_lo,
                                      g0xf, g0hf, g0b, ef, Htb, nullptr, N);
  }
  k_aggmax<<<g4, 256, 0, stream>>>(Htb, offsets, entries, m_hi, N);
  k_gt<1><<<g128, 256, 0, stream>>>(hinit_b, m_hi, h_hi, h_lo,
                                    g1xf, g1hf, g1b, nullptr, nullptr, out, N);
}

// Round 12
// 1055.242 us; speedup vs baseline: 1.1618x; 1.0319x over previous
//
#include <hip/hip_runtime.h>

typedef short v8s __attribute__((ext_vector_type(8)));
typedef float v4f __attribute__((ext_vector_type(4)));

__device__ __forceinline__ unsigned short f2bf(float x) {
  unsigned u = __float_as_uint(x);
  u = u + 0x7FFFu + ((u >> 16) & 1u);
  return (unsigned short)(u >> 16);
}
__device__ __forceinline__ float bf2f(unsigned short b) {
  return __uint_as_float(((unsigned)b) << 16);
}
__device__ __forceinline__ float sigmoidf_(float x) {
  return 1.f / (1.f + __expf(-x));
}
__device__ __forceinline__ float tanhf_(float x) {
  x = fminf(fmaxf(x, -20.f), 20.f);
  float e2 = __expf(2.f * x);
  return (e2 - 1.f) / (e2 + 1.f);
}
// LDS swizzle: XOR byte-bits 4-6 with row&7 (rows are 128 B) -> 2-way max.
__device__ __forceinline__ int swz(int row, int byteInRow) {
  return row * 128 + (byteInRow ^ ((row & 7) << 4));
}

// ---------- weight prep (device) ----------
// frag layout per weight: idx = ((p*nkc + kc)*nct + ct)*512 + lane*8 + j
// value: W[t][kc*32+(lane>>4)*8+j][ct*16+(lane&15)], p=0 hi, p=1 lo.
__device__ __forceinline__ void wprep_one(const float* W, unsigned short* O,
                                          int K, int J, int idx) {
  int nkc = K >> 5, nct = J >> 4;
  int j = idx & 7, lane = (idx >> 3) & 63;
  int rest = idx >> 9;
  int ct = rest % nct; rest /= nct;
  int kc = rest % nkc; rest /= nkc;
  int p = rest & 1, t = rest >> 1;
  int row = kc * 32 + (lane >> 4) * 8 + j;
  int col = ct * 16 + (lane & 15);
  float v = W[(size_t)t * K * J + (size_t)row * J + col];
  unsigned short hi = f2bf(v);
  O[idx] = p ? f2bf(v - bf2f(hi)) : hi;
}

// ---------- setup1: counts || embed || wprep (block-partitioned) ----------
__global__ __launch_bounds__(256) void k_setup1(
    const int* __restrict__ adj, int* __restrict__ counts, int E, int ex,
    const int* __restrict__ toks, const float* __restrict__ embed,
    unsigned short* __restrict__ eh, unsigned short* __restrict__ el, int N, int g4,
    const float* eW0, const float* eW1, const float* projW,
    const float* g0Wx, const float* g0Wh, const float* g1Wx, const float* g1Wh,
    unsigned short* eW0f, unsigned short* eW1f, unsigned short* projf,
    unsigned short* g0xf, unsigned short* g0hf,
    unsigned short* g1xf, unsigned short* g1hf) {
  int b = blockIdx.x;
  int tid = threadIdx.x;
  if (b < 4 * ex) {
    int t4 = b / ex, eb = b % ex;
    int e = eb * 256 + tid;
    if (e >= E) return;
    int2 ab = *(const int2*)&adj[(size_t)(t4 * E + e) * 2];
    atomicAdd(&counts[ab.y], 1);
    atomicAdd(&counts[ab.x], 1);
    return;
  }
  b -= 4 * ex;
  if (b < g4) {
    int w = tid >> 6, lane = tid & 63;
    int n = b * 4 + w;
    if (n >= N) return;
    float acc = 0.f;
#pragma unroll
    for (int s = 0; s < 5; ++s)
      acc += embed[(size_t)toks[n * 5 + s] * 64 + lane];
    float v = acc * 0.2f;
    unsigned short h = f2bf(v);
    eh[(size_t)n * 64 + lane] = h;
    el[(size_t)n * 64 + lane] = f2bf(v - bf2f(h));
    return;
  }
  b -= g4;
  int rel = b * 256 + tid;
  if (rel < 65536) { wprep_one(eW0, eW0f, 64, 64, rel); return; }
  rel -= 65536;
  if (rel < 65536) { wprep_one(eW1, eW1f, 64, 64, rel); return; }
  rel -= 65536;
  if (rel < 8192)  { wprep_one(projW, projf, 64, 64, rel); return; }
  rel -= 8192;
  if (rel < 24576) { wprep_one(g0Wx, g0xf, 64, 192, rel); return; }
  rel -= 24576;
  if (rel < 24576) { wprep_one(g0Wh, g0hf, 64, 192, rel); return; }
  rel -= 24576;
  if (rel < 49152) { wprep_one(g1Wx, g1xf, 128, 192, rel); return; }
  rel -= 49152;
  if (rel < 24576) { wprep_one(g1Wh, g1hf, 64, 192, rel); return; }
}

// ---------- scan: counts -> offsets[0..n] and cursor copy ----------
__global__ __launch_bounds__(1024) void k_scan(const int* __restrict__ counts,
                                               int* __restrict__ offsets,
                                               int* __restrict__ cursor, int n) {
  __shared__ int part[1024];
  int tid = threadIdx.x;
  int chunk = (((n + 1023) >> 10) + 3) & ~3;
  int begin = tid * chunk;
  int end = min(begin + chunk, n);
  int s = 0;
  int i = begin;
  for (; i + 4 <= end; i += 4) {
    int4 v = *(const int4*)&counts[i];
    s += v.x + v.y + v.z + v.w;
  }
  for (; i < end; ++i) s += counts[i];
  part[tid] = s;
  __syncthreads();
  for (int off = 1; off < 1024; off <<= 1) {
    int v = (tid >= off) ? part[tid - off] : 0;
    __syncthreads();
    part[tid] += v;
    __syncthreads();
  }
  int run = part[tid] - s;
  i = begin;
  for (; i + 4 <= end; i += 4) {
    int4 c = *(const int4*)&counts[i];
    int4 o;
    o.x = run; o.y = run + c.x; o.z = o.y + c.y; o.w = o.z + c.z;
    *(int4*)&offsets[i] = o;
    *(int4*)&cursor[i] = o;
    run = o.w + c.w;
  }
  for (; i < end; ++i) {
    offsets[i] = run; cursor[i] = run; run += counts[i];
  }
  if (tid == 1023) offsets[n] = part[1023];
}

// ---------- setup2: fill || proj (block-partitioned) ----------
__global__ __launch_bounds__(256) void k_setup2(
    const int* __restrict__ adj, int* __restrict__ cursor,
    int* __restrict__ entries, int E, int ex, int N,
    const unsigned short* __restrict__ A0h, const unsigned short* __restrict__ A0l,
    const unsigned short* __restrict__ Wf,
    unsigned short* __restrict__ h_hi, unsigned short* __restrict__ h_lo,
    unsigned short* __restrict__ hinit_b) {
  int b = blockIdx.x;
  int tid = threadIdx.x;
  if (b < 4 * ex) {
    int t4 = b / ex, eb = b % ex;
    int e = eb * 256 + tid;
    if (e >= E) return;
    int2 ab = *(const int2*)&adj[(size_t)(t4 * E + e) * 2];
    int p1 = atomicAdd(&cursor[ab.y], 1);
    entries[p1] = t4 * N + ab.x;
    int p2 = atomicAdd(&cursor[ab.x], 1);
    entries[p2] = (t4 + 4) * N + ab.y;
    return;
  }
  b -= 4 * ex;
  int wv = tid >> 6, lane = tid & 63;
  int lr = lane & 15, lg = lane >> 4;
  int m0 = b * 128 + wv * 32;
  v4f acc[2][4] = {};
#pragma unroll
  for (int kc = 0; kc < 2; ++kc) {
    v8s ah[2], al[2];
#pragma unroll
    for (int mt = 0; mt < 2; ++mt) {
      int row = min(m0 + mt * 16 + lr, N - 1);
      size_t off = (size_t)row * 64 + kc * 32 + lg * 8;
      ah[mt] = *(const v8s*)&A0h[off];
      al[mt] = *(const v8s*)&A0l[off];
    }
#pragma unroll
    for (int ct = 0; ct < 4; ++ct) {
      v8s bh = *(const v8s*)&Wf[((size_t)(kc * 4 + ct)) * 512 + lane * 8];
      v8s bl = *(const v8s*)&Wf[((size_t)((2 + kc) * 4 + ct)) * 512 + lane * 8];
#pragma unroll
      for (int mt = 0; mt < 2; ++mt) {
        acc[mt][ct] = __builtin_amdgcn_mfma_f32_16x16x32_bf16(ah[mt], bh, acc[mt][ct], 0, 0, 0);
        acc[mt][ct] = __builtin_amdgcn_mfma_f32_16x16x32_bf16(al[mt], bh, acc[mt][ct], 0, 0, 0);
        acc[mt][ct] = __builtin_amdgcn_mfma_f32_16x16x32_bf16(ah[mt], bl, acc[mt][ct], 0, 0, 0);
      }
    }
  }
#pragma unroll
  for (int ct = 0; ct < 4; ++ct)
#pragma unroll
    for (int mt = 0; mt < 2; ++mt)
#pragma unroll
      for (int r = 0; r < 4; ++r) {
        int m = m0 + mt * 16 + lg * 4 + r;
        if (m >= N) continue;
        int col = ct * 16 + lr;
        float v = acc[mt][ct][r];
        unsigned short hb = f2bf(v);
        h_hi[(size_t)m * 64 + col] = hb;
        h_lo[(size_t)m * 64 + col] = f2bf(v - bf2f(hb));
        hinit_b[(size_t)m * 64 + col] = hb;
      }
}

// ---------- initial transform: Ht[t][n] = h[n] @ W[t], 2 types per block ----------
__global__ __launch_bounds__(256) void k_mm_t(
    const unsigned short* __restrict__ A0h, const unsigned short* __restrict__ A0l,
    const unsigned short* __restrict__ Wf, unsigned short* __restrict__ C16,
    int N) {
  int tid = threadIdx.x;
  int wv = tid >> 6, lane = tid & 63;
  int lr = lane & 15, lg = lane >> 4;
  int y = blockIdx.y;
  const unsigned short* W0 = Wf + (size_t)y * 8192;
  const unsigned short* W1 = Wf + (size_t)(y + 4) * 8192;
  unsigned short* C0 = C16 + (size_t)y * N * 64;
  unsigned short* C1 = C16 + (size_t)(y + 4) * N * 64;
  int m0 = blockIdx.x * 128 + wv * 32;
  v4f acc0[2][4] = {}, acc1[2][4] = {};
#pragma unroll
  for (int kc = 0; kc < 2; ++kc) {
    v8s ah[2], al[2];
#pragma unroll
    for (int mt = 0; mt < 2; ++mt) {
      int row = min(m0 + mt * 16 + lr, N - 1);
      size_t off = (size_t)row * 64 + kc * 32 + lg * 8;
      ah[mt] = *(const v8s*)&A0h[off];
      al[mt] = *(const v8s*)&A0l[off];
    }
#pragma unroll
    for (int ct = 0; ct < 4; ++ct) {
      v8s bh0 = *(const v8s*)&W0[((size_t)(kc * 4 + ct)) * 512 + lane * 8];
      v8s bl0 = *(const v8s*)&W0[((size_t)((2 + kc) * 4 + ct)) * 512 + lane * 8];
      v8s bh1 = *(const v8s*)&W1[((size_t)(kc * 4 + ct)) * 512 + lane * 8];
      v8s bl1 = *(const v8s*)&W1[((size_t)((2 + kc) * 4 + ct)) * 512 + lane * 8];
#pragma unroll
      for (int mt = 0; mt < 2; ++mt) {
        acc0[mt][ct] = __builtin_amdgcn_mfma_f32_16x16x32_bf16(ah[mt], bh0, acc0[mt][ct], 0, 0, 0);
        acc0[mt][ct] = __builtin_amdgcn_mfma_f32_16x16x32_bf16(al[mt], bh0, acc0[mt][ct], 0, 0, 0);
        acc0[mt][ct] = __builtin_amdgcn_mfma_f32_16x16x32_bf16(ah[mt], bl0, acc0[mt][ct], 0, 0, 0);
        acc1[mt][ct] = __builtin_amdgcn_mfma_f32_16x16x32_bf16(ah[mt], bh1, acc1[mt][ct], 0, 0, 0);
        acc1[mt][ct] = __builtin_amdgcn_mfma_f32_16x16x32_bf16(al[mt], bh1, acc1[mt][ct], 0, 0, 0);
        acc1[mt][ct] = __builtin_amdgcn_mfma_f32_16x16x32_bf16(ah[mt], bl1, acc1[mt][ct], 0, 0, 0);
      }
    }
  }
#pragma unroll
  for (int ct = 0; ct < 4; ++ct)
#pragma unroll
    for (int mt = 0; mt < 2; ++mt)
#pragma unroll
      for (int r = 0; r < 4; ++r) {
        int m = m0 + mt * 16 + lg * 4 + r;
        if (m < N) {
          C0[(size_t)m * 64 + ct * 16 + lr] = f2bf(acc0[mt][ct][r]);
          C1[(size_t)m * 64 + ct * 16 + lr] = f2bf(acc1[mt][ct][r]);
        }
      }
}

// ---------- segment-max: 32 entries per round, 8 gathers in flight ----------
// Load: lanes 0..31 hold entries[i+lane]; group g gets its 8 rows via shfl
// from lanes g+4k. One dependent chain per ~32-degree node.
__global__ __launch_bounds__(256) void k_aggmax(
    const unsigned short* __restrict__ Htb, const int* __restrict__ offsets,
    const int* __restrict__ entries, unsigned short* __restrict__ mh, int N) {
  int w = threadIdx.x >> 6, lane = threadIdx.x & 63;
  int n = blockIdx.x * 4 + w;
  if (n >= N) return;
  int beg = offsets[n], end = offsets[n + 1];
  int g = lane >> 4, q = lane & 15;
  float a0 = -3.4e38f, a1 = a0, a2 = a0, a3 = a0;
  float b0 = a0, b1 = a0, b2 = a0, b3 = a0;
  float c0 = a0, c1 = a0, c2 = a0, c3 = a0;
  float d0 = a0, d1 = a0, d2 = a0, d3 = a0;
  for (int i = beg; i < end; i += 32) {
    int li = min(i + (lane & 31), end - 1);  // clamped dups harmless for max
    int ei = entries[li];
    int e0 = __shfl(ei, g);
    int e1 = __shfl(ei, g + 4);
    int e2 = __shfl(ei, g + 8);
    int e3 = __shfl(ei, g + 12);
    int e4 = __shfl(ei, g + 16);
    int e5 = __shfl(ei, g + 20);
    int e6 = __shfl(ei, g + 24);
    int e7 = __shfl(ei, g + 28);
    ushort4 v0 = *(const ushort4*)&Htb[(size_t)e0 * 64 + q * 4];
    ushort4 v1 = *(const ushort4*)&Htb[(size_t)e1 * 64 + q * 4];
    ushort4 v2 = *(const ushort4*)&Htb[(size_t)e2 * 64 + q * 4];
    ushort4 v3 = *(const ushort4*)&Htb[(size_t)e3 * 64 + q * 4];
    ushort4 v4 = *(const ushort4*)&Htb[(size_t)e4 * 64 + q * 4];
    ushort4 v5 = *(const ushort4*)&Htb[(size_t)e5 * 64 + q * 4];
    ushort4 v6 = *(const ushort4*)&Htb[(size_t)e6 * 64 + q * 4];
    ushort4 v7 = *(const ushort4*)&Htb[(size_t)e7 * 64 + q * 4];
    a0 = fmaxf(a0, fmaxf(bf2f(v0.x), bf2f(v4.x)));
    a1 = fmaxf(a1, fmaxf(bf2f(v0.y), bf2f(v4.y)));
    a2 = fmaxf(a2, fmaxf(bf2f(v0.z), bf2f(v4.z)));
    a3 = fmaxf(a3, fmaxf(bf2f(v0.w), bf2f(v4.w)));
    b0 = fmaxf(b0, fmaxf(bf2f(v1.x), bf2f(v5.x)));
    b1 = fmaxf(b1, fmaxf(bf2f(v1.y), bf2f(v5.y)));
    b2 = fmaxf(b2, fmaxf(bf2f(v1.z), bf2f(v5.z)));
    b3 = fmaxf(b3, fmaxf(bf2f(v1.w), bf2f(v5.w)));
    c0 = fmaxf(c0, fmaxf(bf2f(v2.x), bf2f(v6.x)));
    c1 = fmaxf(c1, fmaxf(bf2f(v2.y), bf2f(v6.y)));
    c2 = fmaxf(c2, fmaxf(bf2f(v2.z), bf2f(v6.z)));
    c3 = fmaxf(c3, fmaxf(bf2f(v2.w), bf2f(v6.w)));
    d0 = fmaxf(d0, fmaxf(bf2f(v3.x), bf2f(v7.x)));
    d1 = fmaxf(d1, fmaxf(bf2f(v3.y), bf2f(v7.y)));
    d2 = fmaxf(d2, fmaxf(bf2f(v3.z), bf2f(v7.z)));
    d3 = fmaxf(d3, fmaxf(bf2f(v3.w), bf2f(v7.w)));
  }
  a0 = fmaxf(fmaxf(a0, b0), fmaxf(c0, d0));
  a1 = fmaxf(fmaxf(a1, b1), fmaxf(c1, d1));
  a2 = fmaxf(fmaxf(a2, b2), fmaxf(c2, d2));
  a3 = fmaxf(fmaxf(a3, b3), fmaxf(c3, d3));
  a0 = fmaxf(a0, __shfl_xor(a0, 16)); a1 = fmaxf(a1, __shfl_xor(a1, 16));
  a2 = fmaxf(a2, __shfl_xor(a2, 16)); a3 = fmaxf(a3, __shfl_xor(a3, 16));
  a0 = fmaxf(a0, __shfl_xor(a0, 32)); a1 = fmaxf(a1, __shfl_xor(a1, 32));
  a2 = fmaxf(a2, __shfl_xor(a2, 32)); a3 = fmaxf(a3, __shfl_xor(a3, 32));
  if (g == 0) {
    ushort4 o;
    if (end > beg) {
      o.x = f2bf(a0); o.y = f2bf(a1); o.z = f2bf(a2); o.w = f2bf(a3);
    } else {
      o.x = 0; o.y = 0; o.z = 0; o.w = 0;
    }
    *(ushort4*)&mh[(size_t)n * 64 + q * 4] = o;
  }
}

// ---------- fused GRU + next-step transform (same grid, same tile) ----------
// FINAL=0: gru0 (x=msg global), write h, stage new h (single bf16) in LDS,
//          transform -> HtW. FINAL=1: gru1, write f32 out; no transform.
// All LDS rows are wave-local -> NO __syncthreads.
template <int FINAL>
__global__ __launch_bounds__(256) void k_gt(
    const unsigned short* __restrict__ x0, const unsigned short* __restrict__ x1,
    unsigned short* __restrict__ hh, unsigned short* __restrict__ hl,
    const unsigned short* __restrict__ Wxf, const unsigned short* __restrict__ Whf,
    const float* __restrict__ bias, const unsigned short* __restrict__ eWf,
    unsigned short* __restrict__ HtW, float* __restrict__ outF, int N) {
  __shared__ __align__(16) char lds_hs[FINAL ? 16 : 128 * 128]; // 16 KB (hi only)
  int tid = threadIdx.x;
  int wv = tid >> 6, lane = tid & 63;
  int lr = lane & 15, lg = lane >> 4;
  int lbase = wv * 32;
  int m0 = blockIdx.x * 128 + lbase;

  const int NKCX = FINAL ? 4 : 2;
  v4f acc[2][12] = {};   // xr,xu,xc (+hr,hu merged)
  v4f acch[2][4] = {};   // hc separate
#pragma unroll
  for (int kc = 0; kc < NKCX; ++kc) {
    const unsigned short* X = (FINAL && kc >= 2) ? x1 : x0;
    int kcl = kc & 1;
    v8s ax[2];
#pragma unroll
    for (int mt = 0; mt < 2; ++mt) {
      int row = min(m0 + mt * 16 + lr, N - 1);
      ax[mt] = *(const v8s*)&X[(size_t)row * 64 + kcl * 32 + lg * 8];
    }
#pragma unroll
    for (int ct = 0; ct < 12; ++ct) {
      v8s bh = *(const v8s*)&Wxf[((size_t)(kc * 12 + ct)) * 512 + lane * 8];
      v8s bl = *(const v8s*)&Wxf[((size_t)((NKCX + kc) * 12 + ct)) * 512 + lane * 8];
#pragma unroll
      for (int mt = 0; mt < 2; ++mt) {
        acc[mt][ct] = __builtin_amdgcn_mfma_f32_16x16x32_bf16(ax[mt], bh, acc[mt][ct], 0, 0, 0);
        acc[mt][ct] = __builtin_amdgcn_mfma_f32_16x16x32_bf16(ax[mt], bl, acc[mt][ct], 0, 0, 0);
      }
    }
  }
#pragma unroll
  for (int kc = 0; kc < 2; ++kc) {
    v8s ah[2], al[2];
#pragma unroll
    for (int mt = 0; mt < 2; ++mt) {
      int row = min(m0 + mt * 16 + lr, N - 1);
      size_t off = (size_t)row * 64 + kc * 32 + lg * 8;
      ah[mt] = *(const v8s*)&hh[off];
      al[mt] = *(const v8s*)&hl[off];
    }
#pragma unroll
    for (int ct = 0; ct < 12; ++ct) {
      v8s bh = *(const v8s*)&Whf[((size_t)(kc * 12 + ct)) * 512 + lane * 8];
      v8s bl = *(const v8s*)&Whf[((size_t)((2 + kc) * 12 + ct)) * 512 + lane * 8];
#pragma unroll
      for (int mt = 0; mt < 2; ++mt) {
        v4f* d = (ct < 8) ? &acc[mt][ct] : &acch[mt][ct - 8];
        *d = __builtin_amdgcn_mfma_f32_16x16x32_bf16(ah[mt], bh, *d, 0, 0, 0);
        *d = __builtin_amdgcn_mfma_f32_16x16x32_bf16(al[mt], bh, *d, 0, 0, 0);
        *d = __builtin_amdgcn_mfma_f32_16x16x32_bf16(ah[mt], bl, *d, 0, 0, 0);
      }
    }
  }
  // gate epilogue
#pragma unroll
  for (int mt = 0; mt < 2; ++mt)
#pragma unroll
    for (int ctg = 0; ctg < 4; ++ctg)
#pragma unroll
      for (int r = 0; r < 4; ++r) {
        int m = m0 + mt * 16 + lg * 4 + r;
        int col = ctg * 16 + lr;
        unsigned short hbv = hh[(size_t)min(m, N - 1) * 64 + col];
        unsigned short hlv = hl[(size_t)min(m, N - 1) * 64 + col];
        float hv = bf2f(hbv) + bf2f(hlv);
        float rr = sigmoidf_(acc[mt][ctg][r] + bias[col]);
        float uu = sigmoidf_(acc[mt][ctg + 4][r] + bias[64 + col]);
        float cc = tanhf_(acc[mt][ctg + 8][r] + bias[128 + col] + rr * acch[mt][ctg][r]);
        float ho = uu * hv + (1.f - uu) * cc;
        if (FINAL) {
          if (m < N) outF[(size_t)m * 64 + col] = ho;
        } else {
          unsigned short ohi = f2bf(ho);
          unsigned short olo = f2bf(ho - bf2f(ohi));
          if (m < N) {
            hh[(size_t)m * 64 + col] = ohi;
            hl[(size_t)m * 64 + col] = olo;
          }
          int row = lbase + mt * 16 + lg * 4 + r;
          *(unsigned short*)(lds_hs + swz(row, col * 2)) = ohi;
        }
      }

  if (FINAL) return;

  // ---- transform new h (single bf16) -> HtW for all 8 types (2 per pass) ----
  v8s tah[2][2];  // [kc][mt]
#pragma unroll
  for (int kc = 0; kc < 2; ++kc)
#pragma unroll
    for (int mt = 0; mt < 2; ++mt) {
      int row = lbase + mt * 16 + lr;
      tah[kc][mt] = *(const v8s*)(lds_hs + swz(row, kc * 64 + lg * 16));
    }
#pragma unroll
  for (int y = 0; y < 4; ++y) {
    const unsigned short* W0 = eWf + (size_t)y * 8192;
    const unsigned short* W1 = eWf + (size_t)(y + 4) * 8192;
    unsigned short* C0 = HtW + (size_t)y * N * 64;
    unsigned short* C1 = HtW + (size_t)(y + 4) * N * 64;
    v4f acc0[2][4] = {}, acc1[2][4] = {};
#pragma unroll
    for (int kc = 0; kc < 2; ++kc)
#pragma unroll
      for (int ct = 0; ct < 4; ++ct) {
        v8s bh0 = *(const v8s*)&W0[((size_t)(kc * 4 + ct)) * 512 + lane * 8];
        v8s bl0 = *(const v8s*)&W0[((size_t)((2 + kc) * 4 + ct)) * 512 + lane * 8];
        v8s bh1 = *(const v8s*)&W1[((size_t)(kc * 4 + ct)) * 512 + lane * 8];
        v8s bl1 = *(const v8s*)&W1[((size_t)((2 + kc) * 4 + ct)) * 512 + lane * 8];
#pragma unroll
        for (int mt = 0; mt < 2; ++mt) {
          acc0[mt][ct] = __builtin_amdgcn_mfma_f32_16x16x32_bf16(tah[kc][mt], bh0, acc0[mt][ct], 0, 0, 0);
          acc0[mt][ct] = __builtin_amdgcn_mfma_f32_16x16x32_bf16(tah[kc][mt], bl0, acc0[mt][ct], 0, 0, 0);
          acc1[mt][ct] = __builtin_amdgcn_mfma_f32_16x16x32_bf16(tah[kc][mt], bh1, acc1[mt][ct], 0, 0, 0);
          acc1[mt][ct] = __builtin_amdgcn_mfma_f32_16x16x32_bf16(tah[kc][mt], bl1, acc1[mt][ct], 0, 0, 0);
        }
      }
#pragma unroll
    for (int ct = 0; ct < 4; ++ct)
#pragma unroll
      for (int mt = 0; mt < 2; ++mt)
#pragma unroll
        for (int r = 0; r < 4; ++r) {
          int m = m0 + mt * 16 + lg * 4 + r;
          if (m < N) {
            C0[(size_t)m * 64 + ct * 16 + lr] = f2bf(acc0[mt][ct][r]);
            C1[(size_t)m * 64 + ct * 16 + lr] = f2bf(acc1[mt][ct][r]);
          }
        }
  }
}

extern "C" void kernel_launch(void* const* d_in, const int* in_sizes, int n_in,
                              void* d_out, int out_size, void* d_ws, size_t ws_size,
                              hipStream_t stream) {
  const int*   toks  = (const int*)d_in[0];
  const int*   adj   = (const int*)d_in[1];
  const float* embed = (const float*)d_in[2];
  const float* projW = (const float*)d_in[3];
  const float* eW0   = (const float*)d_in[4];
  const float* eW1   = (const float*)d_in[5];
  const float* g0Wx  = (const float*)d_in[6];
  const float* g0Wh  = (const float*)d_in[7];
  const float* g0b   = (const float*)d_in[8];
  const float* g1Wx  = (const float*)d_in[9];
  const float* g1Wh  = (const float*)d_in[10];
  const float* g1b   = (const float*)d_in[11];
  float* out = (float*)d_out;

  int N = in_sizes[0] / 5;
  int E = in_sizes[1] / 8;
  size_t ND = (size_t)N * 64;

  char* p = (char*)d_ws;
  unsigned short* Htb     = (unsigned short*)p; p += 8 * ND * 2;   // 61.4 MB
  unsigned short* h_hi    = (unsigned short*)p; p += ND * 2;
  unsigned short* h_lo    = (unsigned short*)p; p += ND * 2;
  unsigned short* hinit_b = (unsigned short*)p; p += ND * 2;
  unsigned short* m_hi    = (unsigned short*)p; p += ND * 2;
  int* offsets = (int*)p; p += (size_t)(N + 64) * sizeof(int);
  int* cnt_cur = (int*)p; p += (size_t)(N + 64) * sizeof(int);
  int* entries = (int*)p; p += (size_t)8 * E * sizeof(int);
  unsigned short* eW0f  = (unsigned short*)p; p += 65536 * 2;
  unsigned short* eW1f  = (unsigned short*)p; p += 65536 * 2;
  unsigned short* projf = (unsigned short*)p; p += 8192 * 2;
  unsigned short* g0xf  = (unsigned short*)p; p += 24576 * 2;
  unsigned short* g0hf  = (unsigned short*)p; p += 24576 * 2;
  unsigned short* g1xf  = (unsigned short*)p; p += 49152 * 2;
  unsigned short* g1hf  = (unsigned short*)p; p += 24576 * 2;
  if ((size_t)(p - (char*)d_ws) > ws_size) return;

  // init-phase aliases inside Htb (consumed by proj before k_mm_t writes Htb)
  unsigned short* emb_h = Htb;
  unsigned short* emb_l = Htb + ND;

  int g128 = (N + 127) / 128;
  int g4 = (N + 3) / 4;
  int ex = (E + 255) / 256;

  hipMemsetAsync(cnt_cur, 0, (size_t)N * sizeof(int), stream);
  k_setup1<<<4 * ex + g4 + 1024, 256, 0, stream>>>(
      adj, cnt_cur, E, ex, toks, embed, emb_h, emb_l, N, g4,
      eW0, eW1, projW, g0Wx, g0Wh, g1Wx, g1Wh,
      eW0f, eW1f, projf, g0xf, g0hf, g1xf, g1hf);
  k_scan<<<1, 1024, 0, stream>>>(cnt_cur, offsets, cnt_cur, N);
  k_setup2<<<4 * ex + g128, 256, 0, stream>>>(
      adj, cnt_cur, entries, E, ex, N,
      emb_h, emb_l, projf, h_hi, h_lo, hinit_b);
  k_mm_t<<<dim3(g128, 4), 256, 0, stream>>>(h_hi, h_lo, eW0f, Htb, N);

  for (int it = 0; it < 7; ++it) {
    k_aggmax<<<g4, 256, 0, stream>>>(Htb, offsets, entries, m_hi, N);
    const unsigned short* ef = (it < 6) ? eW0f : eW1f;
    k_gt<0><<<g128, 256, 0, stream>>>(m_hi, nullptr, h_hi, h_lo,
                                      g0xf, g0hf, g0b, ef, Htb, nullptr, N);
  }
  k_aggmax<<<g4, 256, 0, stream>>>(Htb, offsets, entries, m_hi, N);
  k_gt<1><<<g128, 256, 0, stream>>>(hinit_b, m_hi, h_hi, h_lo,
                                    g1xf, g1hf, g1b, nullptr, nullptr, out, N);
}